// Round 19
// baseline (157.629 us; speedup 1.0000x reference)
//
#include <hip/hip_runtime.h>
#include <hip/hip_bf16.h>
#include <math.h>

#define D_MODEL 512
#define D_INNER 1024
#define D_STATE 16
#define DT_RANK 32
#define B_SZ 2
#define SEQ 2048
#define ROWS (B_SZ*SEQ)   // 4096
#define EPSV 1e-5f
#define NCHUNK 64
#define CLEN (SEQ/NCHUNK)    // 32
#define NPAIR (B_SZ*D_INNER) // 2048
#define LOG2E 1.44269504088896f
#define N_ALL 1152           // 1024 dt cols + 32 BC cols + 96 zero pad

typedef short bf16x8 __attribute__((ext_vector_type(8)));
typedef float f32x4  __attribute__((ext_vector_type(4)));
typedef __hip_bfloat16 bf16_t;

static __device__ __forceinline__ float bf2f(bf16_t v) { return __bfloat162float(v); }
static __device__ __forceinline__ float bfraw2f(short v) {
    return __uint_as_float(((unsigned)(unsigned short)v) << 16);
}

// bijective XCD-aware swizzle (all grids have nwg % 8 == 0)
static __device__ __forceinline__ void xcd_swizzle(int& bx, int& by) {
    int gx = gridDim.x;
    int nwg = gx * gridDim.y;
    int flat = by * gx + bx;
    int q = nwg >> 3;
    int s = (flat & 7) * q + (flat >> 3);
    bx = s % gx; by = s / gx;
}

// ================= fused prep: weight converts + Wc GEMM + W_all tail + RMSNorm ========
__global__ __launch_bounds__(256) void prep_kernel(
        const float* __restrict__ in_proj_w, const float* __restrict__ out_proj_w,
        const float* __restrict__ dt_proj_w, const float* __restrict__ x_proj_w,
        const float* __restrict__ x, const int* __restrict__ mask,
        const float* __restrict__ norm_w,
        bf16_t* __restrict__ w_in, bf16_t* __restrict__ w_out,
        bf16_t* __restrict__ W_all, bf16_t* __restrict__ h) {
    int bid = blockIdx.x;
    int tid = threadIdx.x;
    if (bid < 1536) {                       // weight conversion
        const float* src = (bid < 1024) ? in_proj_w : out_proj_w;
        bf16_t* dst = (bid < 1024) ? w_in : w_out;
        int i = ((bid < 1024) ? bid : (bid - 1024)) * 256 + tid;
        float4 v = reinterpret_cast<const float4*>(src)[i];
        bf16_t o[4] = {__float2bfloat16(v.x), __float2bfloat16(v.y),
                       __float2bfloat16(v.z), __float2bfloat16(v.w)};
        reinterpret_cast<ushort4*>(dst)[i] = *reinterpret_cast<ushort4*>(o);
    } else if (bid < 1792) {                // Wc = dt_proj_w @ x_proj_w[0:32,:]
        __shared__ float a[64][33];
        __shared__ float b[32][68];
        int blk = bid - 1536;
        int n0 = (blk >> 4) * 64;
        int k0 = (blk & 15) * 64;
        #pragma unroll
        for (int hh = 0; hh < 2; ++hh) {
            int q = tid + hh * 256;
            int r = q >> 3, c = (q & 7) * 4;
            float4 v = *reinterpret_cast<const float4*>(dt_proj_w + (size_t)(n0 + r) * DT_RANK + c);
            a[r][c] = v.x; a[r][c + 1] = v.y; a[r][c + 2] = v.z; a[r][c + 3] = v.w;
            int r2 = q >> 4, c2 = (q & 15) * 4;
            float4 w = *reinterpret_cast<const float4*>(x_proj_w + (size_t)r2 * D_INNER + k0 + c2);
            b[r2][c2] = w.x; b[r2][c2 + 1] = w.y; b[r2][c2 + 2] = w.z; b[r2][c2 + 3] = w.w;
        }
        __syncthreads();
        int ty = tid >> 4, tx = tid & 15;
        float acc[4][4] = {};
        #pragma unroll
        for (int r = 0; r < 32; ++r) {
            float av[4], bv[4];
            #pragma unroll
            for (int i = 0; i < 4; ++i) av[i] = a[ty * 4 + i][r];
            #pragma unroll
            for (int j = 0; j < 4; ++j) bv[j] = b[r][tx * 4 + j];
            #pragma unroll
            for (int i = 0; i < 4; ++i)
                #pragma unroll
                for (int j = 0; j < 4; ++j)
                    acc[i][j] = fmaf(av[i], bv[j], acc[i][j]);
        }
        #pragma unroll
        for (int i = 0; i < 4; ++i) {
            bf16_t o[4];
            #pragma unroll
            for (int j = 0; j < 4; ++j) o[j] = __float2bfloat16(acc[i][j]);
            *reinterpret_cast<ushort4*>(W_all + (size_t)(n0 + ty * 4 + i) * D_INNER + k0 + tx * 4) =
                *reinterpret_cast<ushort4*>(o);
        }
    } else if (bid < 1920) {                // W_all rows [1024,1152): 32 BC rows + 96 zero
        int row = bid - 1792;               // one row per block
        int cq = tid * 4;
        bf16_t o[4] = {};
        if (row < 32) {
            float4 v = *reinterpret_cast<const float4*>(x_proj_w + (size_t)(32 + row) * D_INNER + cq);
            o[0] = __float2bfloat16(v.x); o[1] = __float2bfloat16(v.y);
            o[2] = __float2bfloat16(v.z); o[3] = __float2bfloat16(v.w);
        }
        *reinterpret_cast<ushort4*>(W_all + (size_t)(1024 + row) * D_INNER + cq) =
            *reinterpret_cast<ushort4*>(o);
    } else {                                // RMSNorm + mask -> bf16 h
        __shared__ float red[4];
        int row = bid - 1920;
        const float2 v = reinterpret_cast<const float2*>(x + (size_t)row * D_MODEL)[tid];
        float ss = v.x * v.x + v.y * v.y;
        #pragma unroll
        for (int m = 1; m < 64; m <<= 1) ss += __shfl_xor(ss, m);
        if ((tid & 63) == 0) red[tid >> 6] = ss;
        __syncthreads();
        float tot = red[0] + red[1] + red[2] + red[3];
        float scale = rsqrtf(tot * (1.0f / D_MODEL) + EPSV) * (float)mask[row];
        __hip_bfloat162 o;
        o.x = __float2bfloat16(v.x * scale * norm_w[2 * tid]);
        o.y = __float2bfloat16(v.y * scale * norm_w[2 * tid + 1]);
        reinterpret_cast<__hip_bfloat162*>(h + (size_t)row * D_MODEL)[tid] = o;
    }
}

// ---------------- bf16 MFMA GEMM, 64x128 tile, 2 waves, BK=64, single-buffer ----------
// Each wave owns a 64x64 output sub-tile (wr=0, wc=wid*64) -> same 32 FLOP/LDS-byte as
// the 128^2 tile, but 2x the blocks and half the barrier width. LDS 24KB -> 6 blocks/CU.
// swapped  mfma(bfr,af): lane's 4 regs = 4 consecutive n at fixed m  -> t-major stores
// nonswap  mfma(af,bfr): lane's 4 regs = 4 consecutive m at fixed n  -> TRANSPOSED stores
// MODE 2: swapped. C fp32 = xres + mask[m]*acc
// MODE 3: n0<1024 swapped -> bf16 u_pre[t][d]; n0>=1024 nonswap -> bf16 silu(z) gT[d][t]
// MODE 4: n0<1024 nonswap -> softplus(v+bias[n]) dtT[d][t]; n0>=1024 swapped -> fp32 bc[t][32]
template<int MODE>
__global__ __launch_bounds__(128, 3) void gemm_mfma(
        const bf16_t* __restrict__ A, const bf16_t* __restrict__ Bw,
        void* __restrict__ Cv, int M, int N, int K,
        const float* __restrict__ xres, const int* __restrict__ mask2,
        void* __restrict__ z2, const float* __restrict__ bias) {
    __shared__ alignas(16) bf16_t As[64 * 64];    //  8 KB
    __shared__ alignas(16) bf16_t Bs[128 * 64];   // 16 KB
    const int tid = threadIdx.x;
    const int wid = tid >> 6, lane = tid & 63;
    int bx = blockIdx.x, by = blockIdx.y;
    xcd_swizzle(bx, by);
    const int m0 = by * 64, n0 = bx * 128;
    const int wc = wid * 64;                      // wave's column half; wr = 0

    const bool ns = (MODE == 3) ? (n0 >= D_INNER)
                  : (MODE == 4) ? (n0 < D_INNER) : false;

    f32x4 acc[4][4];
    #pragma unroll
    for (int i = 0; i < 4; ++i)
        #pragma unroll
        for (int j = 0; j < 4; ++j)
            #pragma unroll
            for (int r = 0; r < 4; ++r) acc[i][j][r] = 0.f;

    const int rrow = lane & 15, kg = lane >> 4;
    const int lrow = lane >> 3;          // 0..7: row within 8-row chunk
    const int cbs = (lane & 7) ^ lrow;   // source colblock (XOR involution on 8 blocks)

    // hoisted LDS read offsets
    int offA[2][4], offB[2][4];
    #pragma unroll
    for (int kk = 0; kk < 2; ++kk) {
        #pragma unroll
        for (int i = 0; i < 4; ++i) {
            int ra = i * 16 + rrow;
            offA[kk][i] = ra * 64 + (((kk * 4 + kg) ^ (ra & 7)) * 8);
        }
        #pragma unroll
        for (int j = 0; j < 4; ++j) {
            int rb = wc + j * 16 + rrow;
            offB[kk][j] = rb * 64 + (((kk * 4 + kg) ^ (rb & 7)) * 8);
        }
    }
    // hoisted per-lane global staging pointers (advance by 64 per K-step)
    const bf16_t* gAp[4];   // A: 8 chunks of 8 rows, split over 2 waves
    const bf16_t* gBp[8];   // B: 16 chunks of 8 rows, split over 2 waves
    #pragma unroll
    for (int j = 0; j < 4; ++j) {
        int r = (wid * 4 + j) * 8 + lrow;
        gAp[j] = A + (size_t)(m0 + r) * K + cbs * 8;
    }
    #pragma unroll
    for (int j = 0; j < 8; ++j) {
        int r = (wid * 8 + j) * 8 + lrow;
        gBp[j] = Bw + (size_t)(n0 + r) * K + cbs * 8;
    }

    auto stage = [&]() {
        #pragma unroll
        for (int j = 0; j < 4; ++j) {
            int c = wid * 4 + j;
            __builtin_amdgcn_global_load_lds(
                (const __attribute__((address_space(1))) void*)gAp[j],
                (__attribute__((address_space(3))) void*)(As + c * 512), 16, 0, 0);
            gAp[j] += 64;
        }
        #pragma unroll
        for (int j = 0; j < 8; ++j) {
            int c = wid * 8 + j;
            __builtin_amdgcn_global_load_lds(
                (const __attribute__((address_space(1))) void*)gBp[j],
                (__attribute__((address_space(3))) void*)(Bs + c * 512), 16, 0, 0);
            gBp[j] += 64;
        }
    };
    auto computeS = [&]() {
        #pragma unroll
        for (int kk = 0; kk < 2; ++kk) {
            bf16x8 af[4], bfr[4];
            #pragma unroll
            for (int i = 0; i < 4; ++i)
                af[i] = *reinterpret_cast<const bf16x8*>(As + offA[kk][i]);
            #pragma unroll
            for (int j = 0; j < 4; ++j)
                bfr[j] = *reinterpret_cast<const bf16x8*>(Bs + offB[kk][j]);
            #pragma unroll
            for (int i = 0; i < 4; ++i)
                #pragma unroll
                for (int j = 0; j < 4; ++j)
                    acc[i][j] = __builtin_amdgcn_mfma_f32_16x16x32_bf16(bfr[j], af[i], acc[i][j], 0, 0, 0);
        }
    };
    auto computeNS = [&]() {
        #pragma unroll
        for (int kk = 0; kk < 2; ++kk) {
            bf16x8 af[4], bfr[4];
            #pragma unroll
            for (int i = 0; i < 4; ++i)
                af[i] = *reinterpret_cast<const bf16x8*>(As + offA[kk][i]);
            #pragma unroll
            for (int j = 0; j < 4; ++j)
                bfr[j] = *reinterpret_cast<const bf16x8*>(Bs + offB[kk][j]);
            #pragma unroll
            for (int i = 0; i < 4; ++i)
                #pragma unroll
                for (int j = 0; j < 4; ++j)
                    acc[i][j] = __builtin_amdgcn_mfma_f32_16x16x32_bf16(af[i], bfr[j], acc[i][j], 0, 0, 0);
        }
    };

    if (ns) {
        for (int k0 = 0; k0 < K; k0 += 64) {
            stage();
            __syncthreads();
            computeNS();
            __syncthreads();
        }
        // transposed epilogue: lane's 4 regs = 4 consecutive m at fixed n
        #pragma unroll
        for (int i = 0; i < 4; ++i) {
            int mb = m0 + i * 16 + (lane >> 4) * 4;
            #pragma unroll
            for (int j = 0; j < 4; ++j) {
                int n = n0 + wc + j * 16 + (lane & 15);
                f32x4 v = acc[i][j];
                bf16_t o[4];
                if (MODE == 3) {          // silu(z) -> gT[d][row]
                    #pragma unroll
                    for (int r = 0; r < 4; ++r) {
                        float zv = v[r];
                        o[r] = __float2bfloat16(zv / (1.f + __expf(-zv)));
                    }
                    *reinterpret_cast<ushort4*>((bf16_t*)z2 + (size_t)(n - D_INNER) * ROWS + mb) =
                        *reinterpret_cast<ushort4*>(o);
                } else {                  // MODE 4: softplus dt -> dtT[d][row]
                    float bs = bias[n];
                    #pragma unroll
                    for (int r = 0; r < 4; ++r) {
                        float s = v[r] + bs;
                        s = (s > 20.f) ? s : __logf(1.f + __expf(s));
                        o[r] = __float2bfloat16(s);
                    }
                    *reinterpret_cast<ushort4*>((bf16_t*)Cv + (size_t)n * ROWS + mb) =
                        *reinterpret_cast<ushort4*>(o);
                }
            }
        }
    } else {
        for (int k0 = 0; k0 < K; k0 += 64) {
            stage();
            __syncthreads();
            computeS();
            __syncthreads();
        }
        // swapped epilogue: lane's 4 regs = 4 consecutive n at fixed m
        #pragma unroll
        for (int i = 0; i < 4; ++i) {
            int m = m0 + i * 16 + (lane & 15);
            #pragma unroll
            for (int j = 0; j < 4; ++j) {
                int nb = n0 + wc + j * 16 + (lane >> 4) * 4;
                f32x4 v = acc[i][j];
                if (MODE == 2) {
                    float mf = (float)mask2[m];
                    float4 xr = *reinterpret_cast<const float4*>(xres + (size_t)m * N + nb);
                    float4 o;
                    o.x = xr.x + mf * v[0]; o.y = xr.y + mf * v[1];
                    o.z = xr.z + mf * v[2]; o.w = xr.w + mf * v[3];
                    *reinterpret_cast<float4*>((float*)Cv + (size_t)m * N + nb) = o;
                } else if (MODE == 3) {   // u_pre half (nb < D_INNER always here)
                    bf16_t o[4];
                    #pragma unroll
                    for (int r = 0; r < 4; ++r) o[r] = __float2bfloat16(v[r]);
                    *reinterpret_cast<ushort4*>((bf16_t*)Cv + (size_t)m * D_INNER + nb) =
                        *reinterpret_cast<ushort4*>(o);
                } else {                  // MODE 4 bc block (nb >= D_INNER always here)
                    if (nb < D_INNER + 32) {
                        float4 o; o.x = v[0]; o.y = v[1]; o.z = v[2]; o.w = v[3];
                        *reinterpret_cast<float4*>((float*)z2 + (size_t)m * 32 + (nb - D_INNER)) = o;
                    }
                }
            }
        }
    }
}

// ---------------- causal depthwise conv (width 4) + bias + SiLU, 8 d per thread ----------
__global__ __launch_bounds__(256) void conv_silu_kernel(const bf16_t* __restrict__ upre,
        const float* __restrict__ conv_w, const float* __restrict__ conv_b,
        bf16_t* __restrict__ u) {
    int idx = blockIdx.x * 256 + threadIdx.x;   // over ROWS*D_INNER/8
    int dq = idx & 127;            // d-group: d0 = dq*8
    int row = idx >> 7;            // b*SEQ + t
    int t = row & (SEQ - 1);
    int d0 = dq * 8;
    const bf16_t* base = upre + (size_t)(row - t) * D_INNER + d0;
    float s_[8];
    {
        float4 b0 = *reinterpret_cast<const float4*>(conv_b + d0);
        float4 b1 = *reinterpret_cast<const float4*>(conv_b + d0 + 4);
        s_[0] = b0.x; s_[1] = b0.y; s_[2] = b0.z; s_[3] = b0.w;
        s_[4] = b1.x; s_[5] = b1.y; s_[6] = b1.z; s_[7] = b1.w;
    }
    #pragma unroll
    for (int j = 0; j < 4; ++j) {
        int tt = t - 3 + j;
        if (tt >= 0) {
            bf16x8 vv = *reinterpret_cast<const bf16x8*>(base + (size_t)tt * D_INNER);
            #pragma unroll
            for (int i = 0; i < 8; ++i)
                s_[i] = fmaf(conv_w[(d0 + i) * 4 + j], bfraw2f(vv[i]), s_[i]);
        }
    }
    bf16_t o[8];
    #pragma unroll
    for (int i = 0; i < 8; ++i) {
        float v = s_[i];
        o[i] = __float2bfloat16(v / (1.f + __expf(-v)));
    }
    *reinterpret_cast<bf16x8*>(u + (size_t)row * D_INNER + d0) =
        *reinterpret_cast<bf16x8*>(o);
}

// ================= chunked selective scan: 2-way split, vector dt/g, LDS-staged u ======
__global__ __launch_bounds__(256) void scan_phase1(
        const bf16_t* __restrict__ dtT, const bf16_t* __restrict__ ub,
        const float* __restrict__ bcbuf, const float* __restrict__ A_log,
        float* __restrict__ P, float* __restrict__ F) {
    int tid = threadIdx.x;
    int bid = blockIdx.x;
    int dblk = bid & 7, c = (bid >> 3) & (NCHUNK - 1), b = bid >> 9;
    int d = dblk * 128 + (tid >> 1);
    int dloc = tid >> 1;
    int sh = (tid & 1) * 8;
    __shared__ float sBC[CLEN][32];
    __shared__ bf16_t sU[CLEN][128];
    size_t rb = (size_t)b * SEQ + (size_t)c * CLEN;
    {
        int row = tid >> 3, q = tid & 7;
        *reinterpret_cast<float4*>(&sBC[row][q * 4]) =
            *reinterpret_cast<const float4*>(bcbuf + (rb + row) * 32 + q * 4);
    }
    {
        int d0 = dblk * 128;
        #pragma unroll
        for (int hh = 0; hh < 2; ++hh) {
            int s = hh * 256 + tid;
            int row = s >> 4, cb = (s & 15) * 8;
            *reinterpret_cast<bf16x8*>(&sU[row][cb]) =
                *reinterpret_cast<const bf16x8*>(ub + (rb + row) * D_INNER + d0 + cb);
        }
    }
    float A2[8];
    #pragma unroll
    for (int s4 = 0; s4 < 2; ++s4) {
        float4 a = *reinterpret_cast<const float4*>(A_log + d * D_STATE + sh + s4 * 4);
        A2[s4 * 4 + 0] = -expf(a.x) * LOG2E;
        A2[s4 * 4 + 1] = -expf(a.y) * LOG2E;
        A2[s4 * 4 + 2] = -expf(a.z) * LOG2E;
        A2[s4 * 4 + 3] = -expf(a.w) * LOG2E;
    }
    float p[8], f[8];
    #pragma unroll
    for (int s = 0; s < 8; ++s) { p[s] = 1.f; f[s] = 0.f; }
    const bf16_t* dtp = dtT + (size_t)d * ROWS + rb;
    __syncthreads();
    bf16x8 dtA = *reinterpret_cast<const bf16x8*>(dtp);
    for (int tb = 0; tb < CLEN; tb += 8) {
        bf16x8 dtB = dtA;
        if (tb + 8 < CLEN) dtB = *reinterpret_cast<const bf16x8*>(dtp + tb + 8);
        #pragma unroll
        for (int j = 0; j < 8; ++j) {
            float dtv = bfraw2f(dtA[j]);
            float dtu = dtv * bf2f(sU[tb + j][dloc]);
            #pragma unroll
            for (int s = 0; s < 8; ++s) {
                float e = exp2f(dtv * A2[s]);
                p[s] *= e;
                f[s] = fmaf(e, f[s], sBC[tb + j][sh + s] * dtu);
            }
        }
        dtA = dtB;
    }
    size_t o = ((size_t)(b * D_INNER + d) * NCHUNK + c) * D_STATE + sh;
    #pragma unroll
    for (int s4 = 0; s4 < 2; ++s4) {
        float4 vp = {p[s4*4+0], p[s4*4+1], p[s4*4+2], p[s4*4+3]};
        float4 vf = {f[s4*4+0], f[s4*4+1], f[s4*4+2], f[s4*4+3]};
        *reinterpret_cast<float4*>(P + o + s4 * 4) = vp;
        *reinterpret_cast<float4*>(F + o + s4 * 4) = vf;
    }
}

// one thread per (pair,s) chain, 8-deep load pipeline; writes Hinit IN PLACE over P
__global__ __launch_bounds__(256) void scan_phase2(
        float* __restrict__ P, const float* __restrict__ F) {
    int idx = blockIdx.x * 256 + threadIdx.x;   // NPAIR*16
    int pair = idx >> 4, s = idx & 15;
    size_t base = (size_t)pair * NCHUNK * D_STATE + s;
    float pp[8], ff[8];
    #pragma unroll
    for (int j = 0; j < 8; ++j) {
        pp[j] = P[base + (size_t)j * D_STATE];
        ff[j] = F[base + (size_t)j * D_STATE];
    }
    float h = 0.f;
    #pragma unroll
    for (int cb = 0; cb < 8; ++cb) {
        #pragma unroll
        for (int j = 0; j < 8; ++j) {
            int c = cb * 8 + j;
            float p = pp[j], f = ff[j];
            if (cb < 7) {
                pp[j] = P[base + (size_t)(c + 8) * D_STATE];
                ff[j] = F[base + (size_t)(c + 8) * D_STATE];
            }
            P[base + (size_t)c * D_STATE] = h;   // Hinit
            h = fmaf(p, h, f);
        }
    }
}

__global__ __launch_bounds__(256) void scan_phase3(
        const bf16_t* __restrict__ dtT, const bf16_t* __restrict__ ub,
        const float* __restrict__ bcbuf, const bf16_t* __restrict__ gT,  // silu(z), [d][row]
        const float* __restrict__ A_log, const float* __restrict__ Dw,
        const float* __restrict__ Hinit, bf16_t* __restrict__ ybuf) {
    int tid = threadIdx.x;
    int bid = blockIdx.x;
    int dblk = bid & 7, c = (bid >> 3) & (NCHUNK - 1), b = bid >> 9;
    int d = dblk * 128 + (tid >> 1);
    int dloc = tid >> 1;
    int sh = (tid & 1) * 8;
    __shared__ float sBC[CLEN][32];
    __shared__ bf16_t sU[CLEN][128];
    size_t rb = (size_t)b * SEQ + (size_t)c * CLEN;
    {
        int row = tid >> 3, q = tid & 7;
        *reinterpret_cast<float4*>(&sBC[row][q * 4]) =
            *reinterpret_cast<const float4*>(bcbuf + (rb + row) * 32 + q * 4);
    }
    {
        int d0 = dblk * 128;
        #pragma unroll
        for (int hh = 0; hh < 2; ++hh) {
            int s = hh * 256 + tid;
            int row = s >> 4, cb = (s & 15) * 8;
            *reinterpret_cast<bf16x8*>(&sU[row][cb]) =
                *reinterpret_cast<const bf16x8*>(ub + (rb + row) * D_INNER + d0 + cb);
        }
    }
    float A2[8];
    #pragma unroll
    for (int s4 = 0; s4 < 2; ++s4) {
        float4 a = *reinterpret_cast<const float4*>(A_log + d * D_STATE + sh + s4 * 4);
        A2[s4 * 4 + 0] = -expf(a.x) * LOG2E;
        A2[s4 * 4 + 1] = -expf(a.y) * LOG2E;
        A2[s4 * 4 + 2] = -expf(a.z) * LOG2E;
        A2[s4 * 4 + 3] = -expf(a.w) * LOG2E;
    }
    float Dd = Dw[d];
    float st[8];
    size_t o = ((size_t)(b * D_INNER + d) * NCHUNK + c) * D_STATE + sh;
    #pragma unroll
    for (int s4 = 0; s4 < 2; ++s4) {
        float4 hv = *reinterpret_cast<const float4*>(Hinit + o + s4 * 4);
        st[s4*4+0] = hv.x; st[s4*4+1] = hv.y; st[s4*4+2] = hv.z; st[s4*4+3] = hv.w;
    }
    const bf16_t* dtp = dtT + (size_t)d * ROWS + rb;
    const bf16_t* gp  = gT  + (size_t)d * ROWS + rb;
    bf16_t* yp = ybuf + rb * D_INNER + d;
    __syncthreads();
    bf16x8 dtA = *reinterpret_cast<const bf16x8*>(dtp);
    bf16x8 gA  = *reinterpret_cast<const bf16x8*>(gp);
    for (int tb = 0; tb < CLEN; tb += 8) {
        bf16x8 dtB = dtA, gB = gA;
        if (tb + 8 < CLEN) {
            dtB = *reinterpret_cast<const bf16x8*>(dtp + tb + 8);
            gB  = *reinterpret_cast<const bf16x8*>(gp + tb + 8);
        }
        #pragma unroll
        for (int j = 0; j < 8; ++j) {
            float dtv = bfraw2f(dtA[j]);
            float uv = bf2f(sU[tb + j][dloc]);
            float dtu = dtv * uv;
            float y = 0.f;
            #pragma unroll
            for (int s = 0; s < 8; ++s) {
                float e = exp2f(dtv * A2[s]);
                st[s] = fmaf(e, st[s], sBC[tb + j][sh + s] * dtu);
                y = fmaf(st[s], sBC[tb + j][16 + sh + s], y);
            }
            y += __shfl_xor(y, 1);       // combine the two state halves of this d
            if ((tid & 1) == 0) {
                yp[(size_t)(tb + j) * D_INNER] =
                    __float2bfloat16((y + Dd * uv) * bfraw2f(gA[j]));
            }
        }
        dtA = dtB; gA = gB;
    }
}

extern "C" void kernel_launch(void* const* d_in, const int* in_sizes, int n_in,
                              void* d_out, int out_size, void* d_ws, size_t ws_size,
                              hipStream_t stream) {
    const float* x          = (const float*)d_in[0];
    const int*   mask       = (const int*)d_in[1];
    const float* norm_w     = (const float*)d_in[2];
    const float* in_proj_w  = (const float*)d_in[3];
    const float* conv_w     = (const float*)d_in[4];
    const float* conv_b     = (const float*)d_in[5];
    const float* x_proj_w   = (const float*)d_in[6];
    const float* dt_proj_w  = (const float*)d_in[7];
    const float* dt_proj_b  = (const float*)d_in[8];
    const float* A_log      = (const float*)d_in[9];
    const float* Dw         = (const float*)d_in[10];
    const float* out_proj_w = (const float*)d_in[11];
    float* out = (float*)d_out;
    float* ws  = (float*)d_ws;

    // workspace layout (float units), lifetime-shared:
    bf16_t* u_pre = (bf16_t*)ws;               // [t][d] 2,097,152 f
    bf16_t* gT    = (bf16_t*)(ws + 2097152);   // silu(z) [d][t], 1,048,576 f used
    bf16_t* u_bf  = (bf16_t*)(ws + 6291456);   // [t][d] 2,097,152 f
    bf16_t* dtT   = (bf16_t*)(ws + 8388608);   // [d][t] 2,097,152 f
    bf16_t* h_bf  = (bf16_t*)(ws + 10485760);  // shared with y (h dead after in_proj)
    bf16_t* y_bf  = (bf16_t*)(ws + 10485760);  // [t][d] 2,097,152 f
    float*  bcbuf = ws + 12582912;             // 131,072 f
    float*  Pbuf  = ws + 12845056;             // 2,097,152 f (w_in aliased; Hinit in place)
    bf16_t* w_in  = (bf16_t*)(ws + 12845056);  // 524,288 f (dead before P written)
    float*  Fbuf  = ws + 14942208;             // 2,097,152 f (W_all aliased)
    bf16_t* W_all = (bf16_t*)(ws + 14942208);  // N_ALL*1024 bf16 = 589,824 f (dead before F)
    bf16_t* w_out = (bf16_t*)(ws + 17039360);  // 262,144 f

    // 0+1. fused prep: weight converts + Wc + tail + RMSNorm
    prep_kernel<<<6016, 256, 0, stream>>>(in_proj_w, out_proj_w, dt_proj_w, x_proj_w,
                                          x, mask, norm_w, w_in, w_out, W_all, h_bf);
    // 2. in_proj MFMA: u half -> bf16 u_pre[t][d]; z half -> bf16 silu(z) gT[d][t]
    gemm_mfma<3><<<dim3(16, 64), 128, 0, stream>>>(
        h_bf, w_in, u_pre, ROWS, 2 * D_INNER, D_MODEL, nullptr, nullptr, gT, nullptr);
    // 3. causal depthwise conv + SiLU -> u bf16 (8 d/thread)
    conv_silu_kernel<<<(ROWS * D_INNER / 8) / 256, 256, 0, stream>>>(u_pre, conv_w, conv_b, u_bf);
    // 4+5. fused x_proj+dt_proj MFMA: dt -> dtT[d][t] (softplus bf16); bc -> bcbuf fp32
    gemm_mfma<4><<<dim3(N_ALL / 128, 64), 128, 0, stream>>>(
        u_bf, W_all, dtT, ROWS, N_ALL, D_INNER, nullptr, nullptr, bcbuf, dt_proj_b);
    // 6. chunked selective scan (2-way state split, vector dt/g, LDS u) -> y bf16
    scan_phase1<<<B_SZ * NCHUNK * 8, 256, 0, stream>>>(dtT, u_bf, bcbuf, A_log, Pbuf, Fbuf);
    scan_phase2<<<NPAIR * D_STATE / 256, 256, 0, stream>>>(Pbuf, Fbuf);
    scan_phase3<<<B_SZ * NCHUNK * 8, 256, 0, stream>>>(dtT, u_bf, bcbuf, gT, A_log, Dw,
                                                       Pbuf, y_bf);
    // 7. out_proj MFMA + residual + mask (64x128 tile, 4x64 -> 256 blocks)
    gemm_mfma<2><<<dim3(4, 64), 128, 0, stream>>>(
        y_bf, w_out, out, ROWS, D_MODEL, D_INNER, x, mask, nullptr, nullptr);
}

// Round 20
// 155.478 us; speedup vs baseline: 1.0138x; 1.0138x over previous
//
#include <hip/hip_runtime.h>
#include <hip/hip_bf16.h>
#include <math.h>

#define D_MODEL 512
#define D_INNER 1024
#define D_STATE 16
#define DT_RANK 32
#define B_SZ 2
#define SEQ 2048
#define ROWS (B_SZ*SEQ)   // 4096
#define EPSV 1e-5f
#define NCHUNK 64
#define CLEN (SEQ/NCHUNK)    // 32
#define NPAIR (B_SZ*D_INNER) // 2048
#define LOG2E 1.44269504088896f
#define N_ALL 1152           // 1024 dt cols + 32 BC cols + 96 zero pad

typedef short bf16x8 __attribute__((ext_vector_type(8)));
typedef float f32x4  __attribute__((ext_vector_type(4)));
typedef __hip_bfloat16 bf16_t;

static __device__ __forceinline__ float bf2f(bf16_t v) { return __bfloat162float(v); }
static __device__ __forceinline__ float bfraw2f(short v) {
    return __uint_as_float(((unsigned)(unsigned short)v) << 16);
}

// bijective XCD-aware swizzle (all grids have nwg % 8 == 0)
static __device__ __forceinline__ void xcd_swizzle(int& bx, int& by) {
    int gx = gridDim.x;
    int nwg = gx * gridDim.y;
    int flat = by * gx + bx;
    int q = nwg >> 3;
    int s = (flat & 7) * q + (flat >> 3);
    bx = s % gx; by = s / gx;
}

// ================= fused prep: weight converts + Wc GEMM + W_all tail + RMSNorm ========
__global__ __launch_bounds__(256) void prep_kernel(
        const float* __restrict__ in_proj_w, const float* __restrict__ out_proj_w,
        const float* __restrict__ dt_proj_w, const float* __restrict__ x_proj_w,
        const float* __restrict__ x, const int* __restrict__ mask,
        const float* __restrict__ norm_w,
        bf16_t* __restrict__ w_in, bf16_t* __restrict__ w_out,
        bf16_t* __restrict__ W_all, bf16_t* __restrict__ h) {
    int bid = blockIdx.x;
    int tid = threadIdx.x;
    if (bid < 1536) {                       // weight conversion
        const float* src = (bid < 1024) ? in_proj_w : out_proj_w;
        bf16_t* dst = (bid < 1024) ? w_in : w_out;
        int i = ((bid < 1024) ? bid : (bid - 1024)) * 256 + tid;
        float4 v = reinterpret_cast<const float4*>(src)[i];
        bf16_t o[4] = {__float2bfloat16(v.x), __float2bfloat16(v.y),
                       __float2bfloat16(v.z), __float2bfloat16(v.w)};
        reinterpret_cast<ushort4*>(dst)[i] = *reinterpret_cast<ushort4*>(o);
    } else if (bid < 1792) {                // Wc = dt_proj_w @ x_proj_w[0:32,:]
        __shared__ float a[64][33];
        __shared__ float b[32][68];
        int blk = bid - 1536;
        int n0 = (blk >> 4) * 64;
        int k0 = (blk & 15) * 64;
        #pragma unroll
        for (int hh = 0; hh < 2; ++hh) {
            int q = tid + hh * 256;
            int r = q >> 3, c = (q & 7) * 4;
            float4 v = *reinterpret_cast<const float4*>(dt_proj_w + (size_t)(n0 + r) * DT_RANK + c);
            a[r][c] = v.x; a[r][c + 1] = v.y; a[r][c + 2] = v.z; a[r][c + 3] = v.w;
            int r2 = q >> 4, c2 = (q & 15) * 4;
            float4 w = *reinterpret_cast<const float4*>(x_proj_w + (size_t)r2 * D_INNER + k0 + c2);
            b[r2][c2] = w.x; b[r2][c2 + 1] = w.y; b[r2][c2 + 2] = w.z; b[r2][c2 + 3] = w.w;
        }
        __syncthreads();
        int ty = tid >> 4, tx = tid & 15;
        float acc[4][4] = {};
        #pragma unroll
        for (int r = 0; r < 32; ++r) {
            float av[4], bv[4];
            #pragma unroll
            for (int i = 0; i < 4; ++i) av[i] = a[ty * 4 + i][r];
            #pragma unroll
            for (int j = 0; j < 4; ++j) bv[j] = b[r][tx * 4 + j];
            #pragma unroll
            for (int i = 0; i < 4; ++i)
                #pragma unroll
                for (int j = 0; j < 4; ++j)
                    acc[i][j] = fmaf(av[i], bv[j], acc[i][j]);
        }
        #pragma unroll
        for (int i = 0; i < 4; ++i) {
            bf16_t o[4];
            #pragma unroll
            for (int j = 0; j < 4; ++j) o[j] = __float2bfloat16(acc[i][j]);
            *reinterpret_cast<ushort4*>(W_all + (size_t)(n0 + ty * 4 + i) * D_INNER + k0 + tx * 4) =
                *reinterpret_cast<ushort4*>(o);
        }
    } else if (bid < 1920) {                // W_all rows [1024,1152): 32 BC rows + 96 zero
        int row = bid - 1792;               // one row per block
        int cq = tid * 4;
        bf16_t o[4] = {};
        if (row < 32) {
            float4 v = *reinterpret_cast<const float4*>(x_proj_w + (size_t)(32 + row) * D_INNER + cq);
            o[0] = __float2bfloat16(v.x); o[1] = __float2bfloat16(v.y);
            o[2] = __float2bfloat16(v.z); o[3] = __float2bfloat16(v.w);
        }
        *reinterpret_cast<ushort4*>(W_all + (size_t)(1024 + row) * D_INNER + cq) =
            *reinterpret_cast<ushort4*>(o);
    } else {                                // RMSNorm + mask -> bf16 h
        __shared__ float red[4];
        int row = bid - 1920;
        const float2 v = reinterpret_cast<const float2*>(x + (size_t)row * D_MODEL)[tid];
        float ss = v.x * v.x + v.y * v.y;
        #pragma unroll
        for (int m = 1; m < 64; m <<= 1) ss += __shfl_xor(ss, m);
        if ((tid & 63) == 0) red[tid >> 6] = ss;
        __syncthreads();
        float tot = red[0] + red[1] + red[2] + red[3];
        float scale = rsqrtf(tot * (1.0f / D_MODEL) + EPSV) * (float)mask[row];
        __hip_bfloat162 o;
        o.x = __float2bfloat16(v.x * scale * norm_w[2 * tid]);
        o.y = __float2bfloat16(v.y * scale * norm_w[2 * tid + 1]);
        reinterpret_cast<__hip_bfloat162*>(h + (size_t)row * D_MODEL)[tid] = o;
    }
}

// ---------------- bf16 MFMA GEMM, 128xTN tile, BK=64, SINGLE-buffer (m97 structure) ----
// launch_bounds(256,3): 16/24 KB LDS -> 3 blocks/CU; cross-block waves hide the
// per-K-step barrier drain (m114 implicit overlap).
// swapped  mfma(bfr,af): lane's 4 regs = 4 consecutive n at fixed m  -> t-major stores
// nonswap  mfma(af,bfr): lane's 4 regs = 4 consecutive m at fixed n  -> TRANSPOSED stores
// MODE 2: swapped. C fp32 = xres + mask[m]*acc
// MODE 3: n0<1024 swapped -> bf16 u_pre[t][d]; n0>=1024 nonswap -> bf16 silu(z) gT[d][t]
// MODE 4: n0<1024 nonswap -> softplus(v+bias[n]) dtT[d][t]; n0>=1024 swapped -> fp32 bc[t][32]
template<int MODE, int TN>
__global__ __launch_bounds__(256, 3) void gemm_mfma(
        const bf16_t* __restrict__ A, const bf16_t* __restrict__ Bw,
        void* __restrict__ Cv, int M, int N, int K,
        const float* __restrict__ xres, const int* __restrict__ mask2,
        void* __restrict__ z2, const float* __restrict__ bias) {
    constexpr int MI  = (TN == 128) ? 4 : 2;   // M-frags per wave
    constexpr int BCH = TN / 32;               // B chunks per wave (chunk = 8 rows x 64 cols)
    __shared__ alignas(16) bf16_t As[128 * 64];
    __shared__ alignas(16) bf16_t Bs[TN * 64];
    const int tid = threadIdx.x;
    const int wid = tid >> 6, lane = tid & 63;
    int bx = blockIdx.x, by = blockIdx.y;
    xcd_swizzle(bx, by);
    const int m0 = by * 128, n0 = bx * TN;
    const int wr = (TN == 128) ? ((wid >> 1) * 64) : (wid * 32);
    const int wc = (TN == 128) ? ((wid & 1) * 64) : 0;

    const bool ns = (MODE == 3) ? (n0 >= D_INNER)
                  : (MODE == 4) ? (n0 < D_INNER) : false;

    f32x4 acc[MI][4];
    #pragma unroll
    for (int i = 0; i < MI; ++i)
        #pragma unroll
        for (int j = 0; j < 4; ++j)
            #pragma unroll
            for (int r = 0; r < 4; ++r) acc[i][j][r] = 0.f;

    const int rrow = lane & 15, kg = lane >> 4;
    const int lrow = lane >> 3;          // 0..7: row within 8-row chunk
    const int cbs = (lane & 7) ^ lrow;   // source colblock (XOR involution on 8 blocks)

    // hoisted LDS read offsets (loop-invariant; static-indexed after unroll)
    int offA[2][MI], offB[2][4];
    #pragma unroll
    for (int kk = 0; kk < 2; ++kk) {
        #pragma unroll
        for (int i = 0; i < MI; ++i) {
            int ra = wr + i * 16 + rrow;
            offA[kk][i] = ra * 64 + (((kk * 4 + kg) ^ (ra & 7)) * 8);
        }
        #pragma unroll
        for (int j = 0; j < 4; ++j) {
            int rb = wc + j * 16 + rrow;
            offB[kk][j] = rb * 64 + (((kk * 4 + kg) ^ (rb & 7)) * 8);
        }
    }
    // hoisted per-lane global staging pointers, advanced by 64 per stage
    const bf16_t* gAp[4];
    const bf16_t* gBp[BCH];
    #pragma unroll
    for (int j = 0; j < 4; ++j) {
        int r = (wid * 4 + j) * 8 + lrow;
        gAp[j] = A + (size_t)(m0 + r) * K + cbs * 8;
    }
    #pragma unroll
    for (int j = 0; j < BCH; ++j) {
        int r = (wid * BCH + j) * 8 + lrow;
        gBp[j] = Bw + (size_t)(n0 + r) * K + cbs * 8;
    }

    auto stage = [&]() {
        #pragma unroll
        for (int j = 0; j < 4; ++j) {
            int c = wid * 4 + j;
            __builtin_amdgcn_global_load_lds(
                (const __attribute__((address_space(1))) void*)gAp[j],
                (__attribute__((address_space(3))) void*)(As + c * 512), 16, 0, 0);
            gAp[j] += 64;
        }
        #pragma unroll
        for (int j = 0; j < BCH; ++j) {
            int c = wid * BCH + j;
            __builtin_amdgcn_global_load_lds(
                (const __attribute__((address_space(1))) void*)gBp[j],
                (__attribute__((address_space(3))) void*)(Bs + c * 512), 16, 0, 0);
            gBp[j] += 64;
        }
    };
    auto computeS = [&]() {
        #pragma unroll
        for (int kk = 0; kk < 2; ++kk) {
            bf16x8 af[MI], bfr[4];
            #pragma unroll
            for (int i = 0; i < MI; ++i)
                af[i] = *reinterpret_cast<const bf16x8*>(As + offA[kk][i]);
            #pragma unroll
            for (int j = 0; j < 4; ++j)
                bfr[j] = *reinterpret_cast<const bf16x8*>(Bs + offB[kk][j]);
            #pragma unroll
            for (int i = 0; i < MI; ++i)
                #pragma unroll
                for (int j = 0; j < 4; ++j)
                    acc[i][j] = __builtin_amdgcn_mfma_f32_16x16x32_bf16(bfr[j], af[i], acc[i][j], 0, 0, 0);
        }
    };
    auto computeNS = [&]() {
        #pragma unroll
        for (int kk = 0; kk < 2; ++kk) {
            bf16x8 af[MI], bfr[4];
            #pragma unroll
            for (int i = 0; i < MI; ++i)
                af[i] = *reinterpret_cast<const bf16x8*>(As + offA[kk][i]);
            #pragma unroll
            for (int j = 0; j < 4; ++j)
                bfr[j] = *reinterpret_cast<const bf16x8*>(Bs + offB[kk][j]);
            #pragma unroll
            for (int i = 0; i < MI; ++i)
                #pragma unroll
                for (int j = 0; j < 4; ++j)
                    acc[i][j] = __builtin_amdgcn_mfma_f32_16x16x32_bf16(af[i], bfr[j], acc[i][j], 0, 0, 0);
        }
    };

    if (ns) {
        for (int k0 = 0; k0 < K; k0 += 64) {
            stage();
            __syncthreads();
            computeNS();
            __syncthreads();
        }
        // transposed epilogue: lane's 4 regs = 4 consecutive m at fixed n
        #pragma unroll
        for (int i = 0; i < MI; ++i) {
            int mb = m0 + wr + i * 16 + (lane >> 4) * 4;
            #pragma unroll
            for (int j = 0; j < 4; ++j) {
                int n = n0 + wc + j * 16 + (lane & 15);
                f32x4 v = acc[i][j];
                bf16_t o[4];
                if (MODE == 3) {          // silu(z) -> gT[d][row]
                    #pragma unroll
                    for (int r = 0; r < 4; ++r) {
                        float zv = v[r];
                        o[r] = __float2bfloat16(zv / (1.f + __expf(-zv)));
                    }
                    *reinterpret_cast<ushort4*>((bf16_t*)z2 + (size_t)(n - D_INNER) * ROWS + mb) =
                        *reinterpret_cast<ushort4*>(o);
                } else {                  // MODE 4: softplus dt -> dtT[d][row]
                    float bs = bias[n];
                    #pragma unroll
                    for (int r = 0; r < 4; ++r) {
                        float s = v[r] + bs;
                        s = (s > 20.f) ? s : __logf(1.f + __expf(s));
                        o[r] = __float2bfloat16(s);
                    }
                    *reinterpret_cast<ushort4*>((bf16_t*)Cv + (size_t)n * ROWS + mb) =
                        *reinterpret_cast<ushort4*>(o);
                }
            }
        }
    } else {
        for (int k0 = 0; k0 < K; k0 += 64) {
            stage();
            __syncthreads();
            computeS();
            __syncthreads();
        }
        // swapped epilogue: lane's 4 regs = 4 consecutive n at fixed m
        #pragma unroll
        for (int i = 0; i < MI; ++i) {
            int m = m0 + wr + i * 16 + (lane & 15);
            #pragma unroll
            for (int j = 0; j < 4; ++j) {
                int nb = n0 + wc + j * 16 + (lane >> 4) * 4;
                f32x4 v = acc[i][j];
                if (MODE == 2) {
                    float mf = (float)mask2[m];
                    float4 xr = *reinterpret_cast<const float4*>(xres + (size_t)m * N + nb);
                    float4 o;
                    o.x = xr.x + mf * v[0]; o.y = xr.y + mf * v[1];
                    o.z = xr.z + mf * v[2]; o.w = xr.w + mf * v[3];
                    *reinterpret_cast<float4*>((float*)Cv + (size_t)m * N + nb) = o;
                } else if (MODE == 3) {   // u_pre half (nb < D_INNER always here)
                    bf16_t o[4];
                    #pragma unroll
                    for (int r = 0; r < 4; ++r) o[r] = __float2bfloat16(v[r]);
                    *reinterpret_cast<ushort4*>((bf16_t*)Cv + (size_t)m * D_INNER + nb) =
                        *reinterpret_cast<ushort4*>(o);
                } else {                  // MODE 4 bc block (nb >= D_INNER always here)
                    if (nb < D_INNER + 32) {
                        float4 o; o.x = v[0]; o.y = v[1]; o.z = v[2]; o.w = v[3];
                        *reinterpret_cast<float4*>((float*)z2 + (size_t)m * 32 + (nb - D_INNER)) = o;
                    }
                }
            }
        }
    }
}

// ---------------- causal depthwise conv (width 4) + bias + SiLU, 8 d per thread ----------
__global__ __launch_bounds__(256) void conv_silu_kernel(const bf16_t* __restrict__ upre,
        const float* __restrict__ conv_w, const float* __restrict__ conv_b,
        bf16_t* __restrict__ u) {
    int idx = blockIdx.x * 256 + threadIdx.x;   // over ROWS*D_INNER/8
    int dq = idx & 127;            // d-group: d0 = dq*8
    int row = idx >> 7;            // b*SEQ + t
    int t = row & (SEQ - 1);
    int d0 = dq * 8;
    const bf16_t* base = upre + (size_t)(row - t) * D_INNER + d0;
    float s_[8];
    {
        float4 b0 = *reinterpret_cast<const float4*>(conv_b + d0);
        float4 b1 = *reinterpret_cast<const float4*>(conv_b + d0 + 4);
        s_[0] = b0.x; s_[1] = b0.y; s_[2] = b0.z; s_[3] = b0.w;
        s_[4] = b1.x; s_[5] = b1.y; s_[6] = b1.z; s_[7] = b1.w;
    }
    #pragma unroll
    for (int j = 0; j < 4; ++j) {
        int tt = t - 3 + j;
        if (tt >= 0) {
            bf16x8 vv = *reinterpret_cast<const bf16x8*>(base + (size_t)tt * D_INNER);
            #pragma unroll
            for (int i = 0; i < 8; ++i)
                s_[i] = fmaf(conv_w[(d0 + i) * 4 + j], bfraw2f(vv[i]), s_[i]);
        }
    }
    bf16_t o[8];
    #pragma unroll
    for (int i = 0; i < 8; ++i) {
        float v = s_[i];
        o[i] = __float2bfloat16(v / (1.f + __expf(-v)));
    }
    *reinterpret_cast<bf16x8*>(u + (size_t)row * D_INNER + d0) =
        *reinterpret_cast<bf16x8*>(o);
}

// ================= chunked selective scan: 2-way split, vector dt/g, LDS-staged u ======
__global__ __launch_bounds__(256) void scan_phase1(
        const bf16_t* __restrict__ dtT, const bf16_t* __restrict__ ub,
        const float* __restrict__ bcbuf, const float* __restrict__ A_log,
        float* __restrict__ P, float* __restrict__ F) {
    int tid = threadIdx.x;
    int bid = blockIdx.x;
    int dblk = bid & 7, c = (bid >> 3) & (NCHUNK - 1), b = bid >> 9;
    int d = dblk * 128 + (tid >> 1);
    int dloc = tid >> 1;
    int sh = (tid & 1) * 8;
    __shared__ float sBC[CLEN][32];
    __shared__ bf16_t sU[CLEN][128];
    size_t rb = (size_t)b * SEQ + (size_t)c * CLEN;
    {
        int row = tid >> 3, q = tid & 7;
        *reinterpret_cast<float4*>(&sBC[row][q * 4]) =
            *reinterpret_cast<const float4*>(bcbuf + (rb + row) * 32 + q * 4);
    }
    {
        int d0 = dblk * 128;
        #pragma unroll
        for (int hh = 0; hh < 2; ++hh) {
            int s = hh * 256 + tid;
            int row = s >> 4, cb = (s & 15) * 8;
            *reinterpret_cast<bf16x8*>(&sU[row][cb]) =
                *reinterpret_cast<const bf16x8*>(ub + (rb + row) * D_INNER + d0 + cb);
        }
    }
    float A2[8];
    #pragma unroll
    for (int s4 = 0; s4 < 2; ++s4) {
        float4 a = *reinterpret_cast<const float4*>(A_log + d * D_STATE + sh + s4 * 4);
        A2[s4 * 4 + 0] = -expf(a.x) * LOG2E;
        A2[s4 * 4 + 1] = -expf(a.y) * LOG2E;
        A2[s4 * 4 + 2] = -expf(a.z) * LOG2E;
        A2[s4 * 4 + 3] = -expf(a.w) * LOG2E;
    }
    float p[8], f[8];
    #pragma unroll
    for (int s = 0; s < 8; ++s) { p[s] = 1.f; f[s] = 0.f; }
    const bf16_t* dtp = dtT + (size_t)d * ROWS + rb;
    __syncthreads();
    bf16x8 dtA = *reinterpret_cast<const bf16x8*>(dtp);
    for (int tb = 0; tb < CLEN; tb += 8) {
        bf16x8 dtB = dtA;
        if (tb + 8 < CLEN) dtB = *reinterpret_cast<const bf16x8*>(dtp + tb + 8);
        #pragma unroll
        for (int j = 0; j < 8; ++j) {
            float dtv = bfraw2f(dtA[j]);
            float dtu = dtv * bf2f(sU[tb + j][dloc]);
            #pragma unroll
            for (int s = 0; s < 8; ++s) {
                float e = exp2f(dtv * A2[s]);
                p[s] *= e;
                f[s] = fmaf(e, f[s], sBC[tb + j][sh + s] * dtu);
            }
        }
        dtA = dtB;
    }
    size_t o = ((size_t)(b * D_INNER + d) * NCHUNK + c) * D_STATE + sh;
    #pragma unroll
    for (int s4 = 0; s4 < 2; ++s4) {
        float4 vp = {p[s4*4+0], p[s4*4+1], p[s4*4+2], p[s4*4+3]};
        float4 vf = {f[s4*4+0], f[s4*4+1], f[s4*4+2], f[s4*4+3]};
        *reinterpret_cast<float4*>(P + o + s4 * 4) = vp;
        *reinterpret_cast<float4*>(F + o + s4 * 4) = vf;
    }
}

// one thread per (pair,s) chain, 8-deep load pipeline; writes Hinit IN PLACE over P
__global__ __launch_bounds__(256) void scan_phase2(
        float* __restrict__ P, const float* __restrict__ F) {
    int idx = blockIdx.x * 256 + threadIdx.x;   // NPAIR*16
    int pair = idx >> 4, s = idx & 15;
    size_t base = (size_t)pair * NCHUNK * D_STATE + s;
    float pp[8], ff[8];
    #pragma unroll
    for (int j = 0; j < 8; ++j) {
        pp[j] = P[base + (size_t)j * D_STATE];
        ff[j] = F[base + (size_t)j * D_STATE];
    }
    float h = 0.f;
    #pragma unroll
    for (int cb = 0; cb < 8; ++cb) {
        #pragma unroll
        for (int j = 0; j < 8; ++j) {
            int c = cb * 8 + j;
            float p = pp[j], f = ff[j];
            if (cb < 7) {
                pp[j] = P[base + (size_t)(c + 8) * D_STATE];
                ff[j] = F[base + (size_t)(c + 8) * D_STATE];
            }
            P[base + (size_t)c * D_STATE] = h;   // Hinit
            h = fmaf(p, h, f);
        }
    }
}

__global__ __launch_bounds__(256) void scan_phase3(
        const bf16_t* __restrict__ dtT, const bf16_t* __restrict__ ub,
        const float* __restrict__ bcbuf, const bf16_t* __restrict__ gT,  // silu(z), [d][row]
        const float* __restrict__ A_log, const float* __restrict__ Dw,
        const float* __restrict__ Hinit, bf16_t* __restrict__ ybuf) {
    int tid = threadIdx.x;
    int bid = blockIdx.x;
    int dblk = bid & 7, c = (bid >> 3) & (NCHUNK - 1), b = bid >> 9;
    int d = dblk * 128 + (tid >> 1);
    int dloc = tid >> 1;
    int sh = (tid & 1) * 8;
    __shared__ float sBC[CLEN][32];
    __shared__ bf16_t sU[CLEN][128];
    size_t rb = (size_t)b * SEQ + (size_t)c * CLEN;
    {
        int row = tid >> 3, q = tid & 7;
        *reinterpret_cast<float4*>(&sBC[row][q * 4]) =
            *reinterpret_cast<const float4*>(bcbuf + (rb + row) * 32 + q * 4);
    }
    {
        int d0 = dblk * 128;
        #pragma unroll
        for (int hh = 0; hh < 2; ++hh) {
            int s = hh * 256 + tid;
            int row = s >> 4, cb = (s & 15) * 8;
            *reinterpret_cast<bf16x8*>(&sU[row][cb]) =
                *reinterpret_cast<const bf16x8*>(ub + (rb + row) * D_INNER + d0 + cb);
        }
    }
    float A2[8];
    #pragma unroll
    for (int s4 = 0; s4 < 2; ++s4) {
        float4 a = *reinterpret_cast<const float4*>(A_log + d * D_STATE + sh + s4 * 4);
        A2[s4 * 4 + 0] = -expf(a.x) * LOG2E;
        A2[s4 * 4 + 1] = -expf(a.y) * LOG2E;
        A2[s4 * 4 + 2] = -expf(a.z) * LOG2E;
        A2[s4 * 4 + 3] = -expf(a.w) * LOG2E;
    }
    float Dd = Dw[d];
    float st[8];
    size_t o = ((size_t)(b * D_INNER + d) * NCHUNK + c) * D_STATE + sh;
    #pragma unroll
    for (int s4 = 0; s4 < 2; ++s4) {
        float4 hv = *reinterpret_cast<const float4*>(Hinit + o + s4 * 4);
        st[s4*4+0] = hv.x; st[s4*4+1] = hv.y; st[s4*4+2] = hv.z; st[s4*4+3] = hv.w;
    }
    const bf16_t* dtp = dtT + (size_t)d * ROWS + rb;
    const bf16_t* gp  = gT  + (size_t)d * ROWS + rb;
    bf16_t* yp = ybuf + rb * D_INNER + d;
    __syncthreads();
    bf16x8 dtA = *reinterpret_cast<const bf16x8*>(dtp);
    bf16x8 gA  = *reinterpret_cast<const bf16x8*>(gp);
    for (int tb = 0; tb < CLEN; tb += 8) {
        bf16x8 dtB = dtA, gB = gA;
        if (tb + 8 < CLEN) {
            dtB = *reinterpret_cast<const bf16x8*>(dtp + tb + 8);
            gB  = *reinterpret_cast<const bf16x8*>(gp + tb + 8);
        }
        #pragma unroll
        for (int j = 0; j < 8; ++j) {
            float dtv = bfraw2f(dtA[j]);
            float uv = bf2f(sU[tb + j][dloc]);
            float dtu = dtv * uv;
            float y = 0.f;
            #pragma unroll
            for (int s = 0; s < 8; ++s) {
                float e = exp2f(dtv * A2[s]);
                st[s] = fmaf(e, st[s], sBC[tb + j][sh + s] * dtu);
                y = fmaf(st[s], sBC[tb + j][16 + sh + s], y);
            }
            y += __shfl_xor(y, 1);       // combine the two state halves of this d
            if ((tid & 1) == 0) {
                yp[(size_t)(tb + j) * D_INNER] =
                    __float2bfloat16((y + Dd * uv) * bfraw2f(gA[j]));
            }
        }
        dtA = dtB; gA = gB;
    }
}

extern "C" void kernel_launch(void* const* d_in, const int* in_sizes, int n_in,
                              void* d_out, int out_size, void* d_ws, size_t ws_size,
                              hipStream_t stream) {
    const float* x          = (const float*)d_in[0];
    const int*   mask       = (const int*)d_in[1];
    const float* norm_w     = (const float*)d_in[2];
    const float* in_proj_w  = (const float*)d_in[3];
    const float* conv_w     = (const float*)d_in[4];
    const float* conv_b     = (const float*)d_in[5];
    const float* x_proj_w   = (const float*)d_in[6];
    const float* dt_proj_w  = (const float*)d_in[7];
    const float* dt_proj_b  = (const float*)d_in[8];
    const float* A_log      = (const float*)d_in[9];
    const float* Dw         = (const float*)d_in[10];
    const float* out_proj_w = (const float*)d_in[11];
    float* out = (float*)d_out;
    float* ws  = (float*)d_ws;

    // workspace layout (float units), lifetime-shared:
    bf16_t* u_pre = (bf16_t*)ws;               // [t][d] 2,097,152 f
    bf16_t* gT    = (bf16_t*)(ws + 2097152);   // silu(z) [d][t], 1,048,576 f used
    bf16_t* u_bf  = (bf16_t*)(ws + 6291456);   // [t][d] 2,097,152 f
    bf16_t* dtT   = (bf16_t*)(ws + 8388608);   // [d][t] 2,097,152 f
    bf16_t* h_bf  = (bf16_t*)(ws + 10485760);  // shared with y (h dead after in_proj)
    bf16_t* y_bf  = (bf16_t*)(ws + 10485760);  // [t][d] 2,097,152 f
    float*  bcbuf = ws + 12582912;             // 131,072 f
    float*  Pbuf  = ws + 12845056;             // 2,097,152 f (w_in aliased; Hinit in place)
    bf16_t* w_in  = (bf16_t*)(ws + 12845056);  // 524,288 f (dead before P written)
    float*  Fbuf  = ws + 14942208;             // 2,097,152 f (W_all aliased)
    bf16_t* W_all = (bf16_t*)(ws + 14942208);  // N_ALL*1024 bf16 = 589,824 f (dead before F)
    bf16_t* w_out = (bf16_t*)(ws + 17039360);  // 262,144 f

    // 0+1. fused prep: weight converts + Wc + tail + RMSNorm
    prep_kernel<<<6016, 256, 0, stream>>>(in_proj_w, out_proj_w, dt_proj_w, x_proj_w,
                                          x, mask, norm_w, w_in, w_out, W_all, h_bf);
    // 2. in_proj MFMA: u half -> bf16 u_pre[t][d]; z half -> bf16 silu(z) gT[d][t]
    gemm_mfma<3, 128><<<dim3(16, 32), 256, 0, stream>>>(
        h_bf, w_in, u_pre, ROWS, 2 * D_INNER, D_MODEL, nullptr, nullptr, gT, nullptr);
    // 3. causal depthwise conv + SiLU -> u bf16 (8 d/thread)
    conv_silu_kernel<<<(ROWS * D_INNER / 8) / 256, 256, 0, stream>>>(u_pre, conv_w, conv_b, u_bf);
    // 4+5. fused x_proj+dt_proj MFMA: dt -> dtT[d][t] (softplus bf16); bc -> bcbuf fp32
    gemm_mfma<4, 128><<<dim3(N_ALL / 128, 32), 256, 0, stream>>>(
        u_bf, W_all, dtT, ROWS, N_ALL, D_INNER, nullptr, nullptr, bcbuf, dt_proj_b);
    // 6. chunked selective scan (2-way state split, vector dt/g, LDS u) -> y bf16
    scan_phase1<<<B_SZ * NCHUNK * 8, 256, 0, stream>>>(dtT, u_bf, bcbuf, A_log, Pbuf, Fbuf);
    scan_phase2<<<NPAIR * D_STATE / 256, 256, 0, stream>>>(Pbuf, Fbuf);
    scan_phase3<<<B_SZ * NCHUNK * 8, 256, 0, stream>>>(dtT, u_bf, bcbuf, gT, A_log, Dw,
                                                       Pbuf, y_bf);
    // 7. out_proj MFMA + residual + mask (128x64 tile, 32x8 -> 256 blocks)
    gemm_mfma<2, 64><<<dim3(8, 32), 256, 0, stream>>>(
        y_bf, w_out, out, ROWS, D_MODEL, D_INNER, x, mask, nullptr, nullptr);
}

// Round 21
// 152.213 us; speedup vs baseline: 1.0356x; 1.0214x over previous
//
#include <hip/hip_runtime.h>
#include <hip/hip_bf16.h>
#include <math.h>

#define D_MODEL 512
#define D_INNER 1024
#define D_STATE 16
#define DT_RANK 32
#define B_SZ 2
#define SEQ 2048
#define ROWS (B_SZ*SEQ)   // 4096
#define EPSV 1e-5f
#define NCHUNK 64
#define CLEN (SEQ/NCHUNK)    // 32
#define NPAIR (B_SZ*D_INNER) // 2048
#define LOG2E 1.44269504088896f
#define N_ALL 1152           // 1024 dt cols + 32 BC cols + 96 zero pad

typedef short bf16x8 __attribute__((ext_vector_type(8)));
typedef float f32x4  __attribute__((ext_vector_type(4)));
typedef __hip_bfloat16 bf16_t;

static __device__ __forceinline__ float bf2f(bf16_t v) { return __bfloat162float(v); }
static __device__ __forceinline__ float bfraw2f(short v) {
    return __uint_as_float(((unsigned)(unsigned short)v) << 16);
}

// bijective XCD-aware swizzle (all grids have nwg % 8 == 0)
static __device__ __forceinline__ void xcd_swizzle(int& bx, int& by) {
    int gx = gridDim.x;
    int nwg = gx * gridDim.y;
    int flat = by * gx + bx;
    int q = nwg >> 3;
    int s = (flat & 7) * q + (flat >> 3);
    bx = s % gx; by = s / gx;
}

// ================= fused prep: weight converts + Wc GEMM + W_all tail + RMSNorm ========
__global__ __launch_bounds__(256) void prep_kernel(
        const float* __restrict__ in_proj_w, const float* __restrict__ out_proj_w,
        const float* __restrict__ dt_proj_w, const float* __restrict__ x_proj_w,
        const float* __restrict__ x, const int* __restrict__ mask,
        const float* __restrict__ norm_w,
        bf16_t* __restrict__ w_in, bf16_t* __restrict__ w_out,
        bf16_t* __restrict__ W_all, bf16_t* __restrict__ h) {
    int bid = blockIdx.x;
    int tid = threadIdx.x;
    if (bid < 1536) {                       // weight conversion
        const float* src = (bid < 1024) ? in_proj_w : out_proj_w;
        bf16_t* dst = (bid < 1024) ? w_in : w_out;
        int i = ((bid < 1024) ? bid : (bid - 1024)) * 256 + tid;
        float4 v = reinterpret_cast<const float4*>(src)[i];
        bf16_t o[4] = {__float2bfloat16(v.x), __float2bfloat16(v.y),
                       __float2bfloat16(v.z), __float2bfloat16(v.w)};
        reinterpret_cast<ushort4*>(dst)[i] = *reinterpret_cast<ushort4*>(o);
    } else if (bid < 1792) {                // Wc = dt_proj_w @ x_proj_w[0:32,:]
        __shared__ float a[64][33];
        __shared__ float b[32][68];
        int blk = bid - 1536;
        int n0 = (blk >> 4) * 64;
        int k0 = (blk & 15) * 64;
        #pragma unroll
        for (int hh = 0; hh < 2; ++hh) {
            int q = tid + hh * 256;
            int r = q >> 3, c = (q & 7) * 4;
            float4 v = *reinterpret_cast<const float4*>(dt_proj_w + (size_t)(n0 + r) * DT_RANK + c);
            a[r][c] = v.x; a[r][c + 1] = v.y; a[r][c + 2] = v.z; a[r][c + 3] = v.w;
            int r2 = q >> 4, c2 = (q & 15) * 4;
            float4 w = *reinterpret_cast<const float4*>(x_proj_w + (size_t)r2 * D_INNER + k0 + c2);
            b[r2][c2] = w.x; b[r2][c2 + 1] = w.y; b[r2][c2 + 2] = w.z; b[r2][c2 + 3] = w.w;
        }
        __syncthreads();
        int ty = tid >> 4, tx = tid & 15;
        float acc[4][4] = {};
        #pragma unroll
        for (int r = 0; r < 32; ++r) {
            float av[4], bv[4];
            #pragma unroll
            for (int i = 0; i < 4; ++i) av[i] = a[ty * 4 + i][r];
            #pragma unroll
            for (int j = 0; j < 4; ++j) bv[j] = b[r][tx * 4 + j];
            #pragma unroll
            for (int i = 0; i < 4; ++i)
                #pragma unroll
                for (int j = 0; j < 4; ++j)
                    acc[i][j] = fmaf(av[i], bv[j], acc[i][j]);
        }
        #pragma unroll
        for (int i = 0; i < 4; ++i) {
            bf16_t o[4];
            #pragma unroll
            for (int j = 0; j < 4; ++j) o[j] = __float2bfloat16(acc[i][j]);
            *reinterpret_cast<ushort4*>(W_all + (size_t)(n0 + ty * 4 + i) * D_INNER + k0 + tx * 4) =
                *reinterpret_cast<ushort4*>(o);
        }
    } else if (bid < 1920) {                // W_all rows [1024,1152): 32 BC rows + 96 zero
        int row = bid - 1792;               // one row per block
        int cq = tid * 4;
        bf16_t o[4] = {};
        if (row < 32) {
            float4 v = *reinterpret_cast<const float4*>(x_proj_w + (size_t)(32 + row) * D_INNER + cq);
            o[0] = __float2bfloat16(v.x); o[1] = __float2bfloat16(v.y);
            o[2] = __float2bfloat16(v.z); o[3] = __float2bfloat16(v.w);
        }
        *reinterpret_cast<ushort4*>(W_all + (size_t)(1024 + row) * D_INNER + cq) =
            *reinterpret_cast<ushort4*>(o);
    } else {                                // RMSNorm + mask -> bf16 h
        __shared__ float red[4];
        int row = bid - 1920;
        const float2 v = reinterpret_cast<const float2*>(x + (size_t)row * D_MODEL)[tid];
        float ss = v.x * v.x + v.y * v.y;
        #pragma unroll
        for (int m = 1; m < 64; m <<= 1) ss += __shfl_xor(ss, m);
        if ((tid & 63) == 0) red[tid >> 6] = ss;
        __syncthreads();
        float tot = red[0] + red[1] + red[2] + red[3];
        float scale = rsqrtf(tot * (1.0f / D_MODEL) + EPSV) * (float)mask[row];
        __hip_bfloat162 o;
        o.x = __float2bfloat16(v.x * scale * norm_w[2 * tid]);
        o.y = __float2bfloat16(v.y * scale * norm_w[2 * tid + 1]);
        reinterpret_cast<__hip_bfloat162*>(h + (size_t)row * D_MODEL)[tid] = o;
    }
}

// ---------------- bf16 MFMA GEMM, 128xTN tile, BK=64, SINGLE-buffer (m97 structure) ----
// launch_bounds(256,3): 16/24 KB LDS -> 3 blocks/CU; cross-block waves hide the
// per-K-step barrier drain (m114 implicit overlap).
// swapped  mfma(bfr,af): lane's 4 regs = 4 consecutive n at fixed m  -> t-major stores
// nonswap  mfma(af,bfr): lane's 4 regs = 4 consecutive m at fixed n  -> TRANSPOSED stores
// MODE 2: swapped. C fp32 = xres + mask[m]*acc
// MODE 3: n0<1024 swapped -> bf16 u_pre[t][d]; n0>=1024 nonswap -> bf16 silu(z) gT[d][t]
// MODE 4: n0<1024 nonswap -> softplus(v+bias[n]) dtT[d][t]; n0>=1024 swapped -> fp32 bc[t][32]
template<int MODE, int TN>
__global__ __launch_bounds__(256, 3) void gemm_mfma(
        const bf16_t* __restrict__ A, const bf16_t* __restrict__ Bw,
        void* __restrict__ Cv, int M, int N, int K,
        const float* __restrict__ xres, const int* __restrict__ mask2,
        void* __restrict__ z2, const float* __restrict__ bias) {
    constexpr int MI  = (TN == 128) ? 4 : 2;   // M-frags per wave
    constexpr int BCH = TN / 32;               // B chunks per wave (chunk = 8 rows x 64 cols)
    __shared__ alignas(16) bf16_t As[128 * 64];
    __shared__ alignas(16) bf16_t Bs[TN * 64];
    const int tid = threadIdx.x;
    const int wid = tid >> 6, lane = tid & 63;
    int bx = blockIdx.x, by = blockIdx.y;
    xcd_swizzle(bx, by);
    const int m0 = by * 128, n0 = bx * TN;
    const int wr = (TN == 128) ? ((wid >> 1) * 64) : (wid * 32);
    const int wc = (TN == 128) ? ((wid & 1) * 64) : 0;

    const bool ns = (MODE == 3) ? (n0 >= D_INNER)
                  : (MODE == 4) ? (n0 < D_INNER) : false;

    f32x4 acc[MI][4];
    #pragma unroll
    for (int i = 0; i < MI; ++i)
        #pragma unroll
        for (int j = 0; j < 4; ++j)
            #pragma unroll
            for (int r = 0; r < 4; ++r) acc[i][j][r] = 0.f;

    const int rrow = lane & 15, kg = lane >> 4;
    const int lrow = lane >> 3;          // 0..7: row within 8-row chunk
    const int cbs = (lane & 7) ^ lrow;   // source colblock (XOR involution on 8 blocks)

    // hoisted LDS read offsets (loop-invariant; static-indexed after unroll)
    int offA[2][MI], offB[2][4];
    #pragma unroll
    for (int kk = 0; kk < 2; ++kk) {
        #pragma unroll
        for (int i = 0; i < MI; ++i) {
            int ra = wr + i * 16 + rrow;
            offA[kk][i] = ra * 64 + (((kk * 4 + kg) ^ (ra & 7)) * 8);
        }
        #pragma unroll
        for (int j = 0; j < 4; ++j) {
            int rb = wc + j * 16 + rrow;
            offB[kk][j] = rb * 64 + (((kk * 4 + kg) ^ (rb & 7)) * 8);
        }
    }
    // hoisted per-lane global staging pointers, advanced by 64 per stage
    const bf16_t* gAp[4];
    const bf16_t* gBp[BCH];
    #pragma unroll
    for (int j = 0; j < 4; ++j) {
        int r = (wid * 4 + j) * 8 + lrow;
        gAp[j] = A + (size_t)(m0 + r) * K + cbs * 8;
    }
    #pragma unroll
    for (int j = 0; j < BCH; ++j) {
        int r = (wid * BCH + j) * 8 + lrow;
        gBp[j] = Bw + (size_t)(n0 + r) * K + cbs * 8;
    }

    auto stage = [&]() {
        #pragma unroll
        for (int j = 0; j < 4; ++j) {
            int c = wid * 4 + j;
            __builtin_amdgcn_global_load_lds(
                (const __attribute__((address_space(1))) void*)gAp[j],
                (__attribute__((address_space(3))) void*)(As + c * 512), 16, 0, 0);
            gAp[j] += 64;
        }
        #pragma unroll
        for (int j = 0; j < BCH; ++j) {
            int c = wid * BCH + j;
            __builtin_amdgcn_global_load_lds(
                (const __attribute__((address_space(1))) void*)gBp[j],
                (__attribute__((address_space(3))) void*)(Bs + c * 512), 16, 0, 0);
            gBp[j] += 64;
        }
    };
    auto computeS = [&]() {
        #pragma unroll
        for (int kk = 0; kk < 2; ++kk) {
            bf16x8 af[MI], bfr[4];
            #pragma unroll
            for (int i = 0; i < MI; ++i)
                af[i] = *reinterpret_cast<const bf16x8*>(As + offA[kk][i]);
            #pragma unroll
            for (int j = 0; j < 4; ++j)
                bfr[j] = *reinterpret_cast<const bf16x8*>(Bs + offB[kk][j]);
            #pragma unroll
            for (int i = 0; i < MI; ++i)
                #pragma unroll
                for (int j = 0; j < 4; ++j)
                    acc[i][j] = __builtin_amdgcn_mfma_f32_16x16x32_bf16(bfr[j], af[i], acc[i][j], 0, 0, 0);
        }
    };
    auto computeNS = [&]() {
        #pragma unroll
        for (int kk = 0; kk < 2; ++kk) {
            bf16x8 af[MI], bfr[4];
            #pragma unroll
            for (int i = 0; i < MI; ++i)
                af[i] = *reinterpret_cast<const bf16x8*>(As + offA[kk][i]);
            #pragma unroll
            for (int j = 0; j < 4; ++j)
                bfr[j] = *reinterpret_cast<const bf16x8*>(Bs + offB[kk][j]);
            #pragma unroll
            for (int i = 0; i < MI; ++i)
                #pragma unroll
                for (int j = 0; j < 4; ++j)
                    acc[i][j] = __builtin_amdgcn_mfma_f32_16x16x32_bf16(af[i], bfr[j], acc[i][j], 0, 0, 0);
        }
    };

    if (ns) {
        for (int k0 = 0; k0 < K; k0 += 64) {
            stage();
            __syncthreads();
            computeNS();
            __syncthreads();
        }
        // transposed epilogue: lane's 4 regs = 4 consecutive m at fixed n
        #pragma unroll
        for (int i = 0; i < MI; ++i) {
            int mb = m0 + wr + i * 16 + (lane >> 4) * 4;
            #pragma unroll
            for (int j = 0; j < 4; ++j) {
                int n = n0 + wc + j * 16 + (lane & 15);
                f32x4 v = acc[i][j];
                bf16_t o[4];
                if (MODE == 3) {          // silu(z) -> gT[d][row]
                    #pragma unroll
                    for (int r = 0; r < 4; ++r) {
                        float zv = v[r];
                        o[r] = __float2bfloat16(zv / (1.f + __expf(-zv)));
                    }
                    *reinterpret_cast<ushort4*>((bf16_t*)z2 + (size_t)(n - D_INNER) * ROWS + mb) =
                        *reinterpret_cast<ushort4*>(o);
                } else {                  // MODE 4: softplus dt -> dtT[d][row]
                    float bs = bias[n];
                    #pragma unroll
                    for (int r = 0; r < 4; ++r) {
                        float s = v[r] + bs;
                        s = (s > 20.f) ? s : __logf(1.f + __expf(s));
                        o[r] = __float2bfloat16(s);
                    }
                    *reinterpret_cast<ushort4*>((bf16_t*)Cv + (size_t)n * ROWS + mb) =
                        *reinterpret_cast<ushort4*>(o);
                }
            }
        }
    } else {
        for (int k0 = 0; k0 < K; k0 += 64) {
            stage();
            __syncthreads();
            computeS();
            __syncthreads();
        }
        // swapped epilogue: lane's 4 regs = 4 consecutive n at fixed m
        #pragma unroll
        for (int i = 0; i < MI; ++i) {
            int m = m0 + wr + i * 16 + (lane & 15);
            #pragma unroll
            for (int j = 0; j < 4; ++j) {
                int nb = n0 + wc + j * 16 + (lane >> 4) * 4;
                f32x4 v = acc[i][j];
                if (MODE == 2) {
                    float mf = (float)mask2[m];
                    float4 xr = *reinterpret_cast<const float4*>(xres + (size_t)m * N + nb);
                    float4 o;
                    o.x = xr.x + mf * v[0]; o.y = xr.y + mf * v[1];
                    o.z = xr.z + mf * v[2]; o.w = xr.w + mf * v[3];
                    *reinterpret_cast<float4*>((float*)Cv + (size_t)m * N + nb) = o;
                } else if (MODE == 3) {   // u_pre half (nb < D_INNER always here)
                    bf16_t o[4];
                    #pragma unroll
                    for (int r = 0; r < 4; ++r) o[r] = __float2bfloat16(v[r]);
                    *reinterpret_cast<ushort4*>((bf16_t*)Cv + (size_t)m * D_INNER + nb) =
                        *reinterpret_cast<ushort4*>(o);
                } else {                  // MODE 4 bc block (nb >= D_INNER always here)
                    if (nb < D_INNER + 32) {
                        float4 o; o.x = v[0]; o.y = v[1]; o.z = v[2]; o.w = v[3];
                        *reinterpret_cast<float4*>((float*)z2 + (size_t)m * 32 + (nb - D_INNER)) = o;
                    }
                }
            }
        }
    }
}

// ---------------- causal depthwise conv (width 4) + bias + SiLU, 8 d per thread ----------
__global__ __launch_bounds__(256) void conv_silu_kernel(const bf16_t* __restrict__ upre,
        const float* __restrict__ conv_w, const float* __restrict__ conv_b,
        bf16_t* __restrict__ u) {
    int idx = blockIdx.x * 256 + threadIdx.x;   // over ROWS*D_INNER/8
    int dq = idx & 127;            // d-group: d0 = dq*8
    int row = idx >> 7;            // b*SEQ + t
    int t = row & (SEQ - 1);
    int d0 = dq * 8;
    const bf16_t* base = upre + (size_t)(row - t) * D_INNER + d0;
    float s_[8];
    {
        float4 b0 = *reinterpret_cast<const float4*>(conv_b + d0);
        float4 b1 = *reinterpret_cast<const float4*>(conv_b + d0 + 4);
        s_[0] = b0.x; s_[1] = b0.y; s_[2] = b0.z; s_[3] = b0.w;
        s_[4] = b1.x; s_[5] = b1.y; s_[6] = b1.z; s_[7] = b1.w;
    }
    #pragma unroll
    for (int j = 0; j < 4; ++j) {
        int tt = t - 3 + j;
        if (tt >= 0) {
            bf16x8 vv = *reinterpret_cast<const bf16x8*>(base + (size_t)tt * D_INNER);
            #pragma unroll
            for (int i = 0; i < 8; ++i)
                s_[i] = fmaf(conv_w[(d0 + i) * 4 + j], bfraw2f(vv[i]), s_[i]);
        }
    }
    bf16_t o[8];
    #pragma unroll
    for (int i = 0; i < 8; ++i) {
        float v = s_[i];
        o[i] = __float2bfloat16(v / (1.f + __expf(-v)));
    }
    *reinterpret_cast<bf16x8*>(u + (size_t)row * D_INNER + d0) =
        *reinterpret_cast<bf16x8*>(o);
}

// ================= chunked selective scan: 2-way split, vector dt/g, LDS-staged u ======
// P/F/Hinit stored in BF16 (chunk-boundary states only; within-chunk math fp32).
__global__ __launch_bounds__(256) void scan_phase1(
        const bf16_t* __restrict__ dtT, const bf16_t* __restrict__ ub,
        const float* __restrict__ bcbuf, const float* __restrict__ A_log,
        bf16_t* __restrict__ P, bf16_t* __restrict__ F) {
    int tid = threadIdx.x;
    int bid = blockIdx.x;
    int dblk = bid & 7, c = (bid >> 3) & (NCHUNK - 1), b = bid >> 9;
    int d = dblk * 128 + (tid >> 1);
    int dloc = tid >> 1;
    int sh = (tid & 1) * 8;
    __shared__ float sBC[CLEN][32];
    __shared__ bf16_t sU[CLEN][128];
    size_t rb = (size_t)b * SEQ + (size_t)c * CLEN;
    {
        int row = tid >> 3, q = tid & 7;
        *reinterpret_cast<float4*>(&sBC[row][q * 4]) =
            *reinterpret_cast<const float4*>(bcbuf + (rb + row) * 32 + q * 4);
    }
    {
        int d0 = dblk * 128;
        #pragma unroll
        for (int hh = 0; hh < 2; ++hh) {
            int s = hh * 256 + tid;
            int row = s >> 4, cb = (s & 15) * 8;
            *reinterpret_cast<bf16x8*>(&sU[row][cb]) =
                *reinterpret_cast<const bf16x8*>(ub + (rb + row) * D_INNER + d0 + cb);
        }
    }
    float A2[8];
    #pragma unroll
    for (int s4 = 0; s4 < 2; ++s4) {
        float4 a = *reinterpret_cast<const float4*>(A_log + d * D_STATE + sh + s4 * 4);
        A2[s4 * 4 + 0] = -expf(a.x) * LOG2E;
        A2[s4 * 4 + 1] = -expf(a.y) * LOG2E;
        A2[s4 * 4 + 2] = -expf(a.z) * LOG2E;
        A2[s4 * 4 + 3] = -expf(a.w) * LOG2E;
    }
    float p[8], f[8];
    #pragma unroll
    for (int s = 0; s < 8; ++s) { p[s] = 1.f; f[s] = 0.f; }
    const bf16_t* dtp = dtT + (size_t)d * ROWS + rb;
    __syncthreads();
    bf16x8 dtA = *reinterpret_cast<const bf16x8*>(dtp);
    for (int tb = 0; tb < CLEN; tb += 8) {
        bf16x8 dtB = dtA;
        if (tb + 8 < CLEN) dtB = *reinterpret_cast<const bf16x8*>(dtp + tb + 8);
        #pragma unroll
        for (int j = 0; j < 8; ++j) {
            float dtv = bfraw2f(dtA[j]);
            float dtu = dtv * bf2f(sU[tb + j][dloc]);
            #pragma unroll
            for (int s = 0; s < 8; ++s) {
                float e = exp2f(dtv * A2[s]);
                p[s] *= e;
                f[s] = fmaf(e, f[s], sBC[tb + j][sh + s] * dtu);
            }
        }
        dtA = dtB;
    }
    size_t o = ((size_t)(b * D_INNER + d) * NCHUNK + c) * D_STATE + sh;
    bf16_t po[8], fo[8];
    #pragma unroll
    for (int s = 0; s < 8; ++s) {
        po[s] = __float2bfloat16(p[s]);
        fo[s] = __float2bfloat16(f[s]);
    }
    *reinterpret_cast<bf16x8*>(P + o) = *reinterpret_cast<bf16x8*>(po);
    *reinterpret_cast<bf16x8*>(F + o) = *reinterpret_cast<bf16x8*>(fo);
}

// one thread per (pair,s) chain, 8-deep load pipeline; writes Hinit IN PLACE over P (bf16)
__global__ __launch_bounds__(256) void scan_phase2(
        bf16_t* __restrict__ P, const bf16_t* __restrict__ F) {
    int idx = blockIdx.x * 256 + threadIdx.x;   // NPAIR*16
    int pair = idx >> 4, s = idx & 15;
    size_t base = (size_t)pair * NCHUNK * D_STATE + s;
    float pp[8], ff[8];
    #pragma unroll
    for (int j = 0; j < 8; ++j) {
        pp[j] = bf2f(P[base + (size_t)j * D_STATE]);
        ff[j] = bf2f(F[base + (size_t)j * D_STATE]);
    }
    float h = 0.f;
    #pragma unroll
    for (int cb = 0; cb < 8; ++cb) {
        #pragma unroll
        for (int j = 0; j < 8; ++j) {
            int c = cb * 8 + j;
            float p = pp[j], f = ff[j];
            if (cb < 7) {
                pp[j] = bf2f(P[base + (size_t)(c + 8) * D_STATE]);
                ff[j] = bf2f(F[base + (size_t)(c + 8) * D_STATE]);
            }
            P[base + (size_t)c * D_STATE] = __float2bfloat16(h);   // Hinit
            h = fmaf(p, h, f);
        }
    }
}

__global__ __launch_bounds__(256) void scan_phase3(
        const bf16_t* __restrict__ dtT, const bf16_t* __restrict__ ub,
        const float* __restrict__ bcbuf, const bf16_t* __restrict__ gT,  // silu(z), [d][row]
        const float* __restrict__ A_log, const float* __restrict__ Dw,
        const bf16_t* __restrict__ Hinit, bf16_t* __restrict__ ybuf) {
    int tid = threadIdx.x;
    int bid = blockIdx.x;
    int dblk = bid & 7, c = (bid >> 3) & (NCHUNK - 1), b = bid >> 9;
    int d = dblk * 128 + (tid >> 1);
    int dloc = tid >> 1;
    int sh = (tid & 1) * 8;
    __shared__ float sBC[CLEN][32];
    __shared__ bf16_t sU[CLEN][128];
    size_t rb = (size_t)b * SEQ + (size_t)c * CLEN;
    {
        int row = tid >> 3, q = tid & 7;
        *reinterpret_cast<float4*>(&sBC[row][q * 4]) =
            *reinterpret_cast<const float4*>(bcbuf + (rb + row) * 32 + q * 4);
    }
    {
        int d0 = dblk * 128;
        #pragma unroll
        for (int hh = 0; hh < 2; ++hh) {
            int s = hh * 256 + tid;
            int row = s >> 4, cb = (s & 15) * 8;
            *reinterpret_cast<bf16x8*>(&sU[row][cb]) =
                *reinterpret_cast<const bf16x8*>(ub + (rb + row) * D_INNER + d0 + cb);
        }
    }
    float A2[8];
    #pragma unroll
    for (int s4 = 0; s4 < 2; ++s4) {
        float4 a = *reinterpret_cast<const float4*>(A_log + d * D_STATE + sh + s4 * 4);
        A2[s4 * 4 + 0] = -expf(a.x) * LOG2E;
        A2[s4 * 4 + 1] = -expf(a.y) * LOG2E;
        A2[s4 * 4 + 2] = -expf(a.z) * LOG2E;
        A2[s4 * 4 + 3] = -expf(a.w) * LOG2E;
    }
    float Dd = Dw[d];
    float st[8];
    size_t o = ((size_t)(b * D_INNER + d) * NCHUNK + c) * D_STATE + sh;
    {
        bf16x8 hv = *reinterpret_cast<const bf16x8*>(Hinit + o);
        #pragma unroll
        for (int s = 0; s < 8; ++s) st[s] = bfraw2f(hv[s]);
    }
    const bf16_t* dtp = dtT + (size_t)d * ROWS + rb;
    const bf16_t* gp  = gT  + (size_t)d * ROWS + rb;
    bf16_t* yp = ybuf + rb * D_INNER + d;
    __syncthreads();
    bf16x8 dtA = *reinterpret_cast<const bf16x8*>(dtp);
    bf16x8 gA  = *reinterpret_cast<const bf16x8*>(gp);
    for (int tb = 0; tb < CLEN; tb += 8) {
        bf16x8 dtB = dtA, gB = gA;
        if (tb + 8 < CLEN) {
            dtB = *reinterpret_cast<const bf16x8*>(dtp + tb + 8);
            gB  = *reinterpret_cast<const bf16x8*>(gp + tb + 8);
        }
        #pragma unroll
        for (int j = 0; j < 8; ++j) {
            float dtv = bfraw2f(dtA[j]);
            float uv = bf2f(sU[tb + j][dloc]);
            float dtu = dtv * uv;
            float y = 0.f;
            #pragma unroll
            for (int s = 0; s < 8; ++s) {
                float e = exp2f(dtv * A2[s]);
                st[s] = fmaf(e, st[s], sBC[tb + j][sh + s] * dtu);
                y = fmaf(st[s], sBC[tb + j][16 + sh + s], y);
            }
            y += __shfl_xor(y, 1);       // combine the two state halves of this d
            if ((tid & 1) == 0) {
                yp[(size_t)(tb + j) * D_INNER] =
                    __float2bfloat16((y + Dd * uv) * bfraw2f(gA[j]));
            }
        }
        dtA = dtB; gA = gB;
    }
}

extern "C" void kernel_launch(void* const* d_in, const int* in_sizes, int n_in,
                              void* d_out, int out_size, void* d_ws, size_t ws_size,
                              hipStream_t stream) {
    const float* x          = (const float*)d_in[0];
    const int*   mask       = (const int*)d_in[1];
    const float* norm_w     = (const float*)d_in[2];
    const float* in_proj_w  = (const float*)d_in[3];
    const float* conv_w     = (const float*)d_in[4];
    const float* conv_b     = (const float*)d_in[5];
    const float* x_proj_w   = (const float*)d_in[6];
    const float* dt_proj_w  = (const float*)d_in[7];
    const float* dt_proj_b  = (const float*)d_in[8];
    const float* A_log      = (const float*)d_in[9];
    const float* Dw         = (const float*)d_in[10];
    const float* out_proj_w = (const float*)d_in[11];
    float* out = (float*)d_out;
    float* ws  = (float*)d_ws;

    // workspace layout (float units), lifetime-shared:
    bf16_t* u_pre = (bf16_t*)ws;               // [t][d] 2,097,152 f
    bf16_t* gT    = (bf16_t*)(ws + 2097152);   // silu(z) [d][t], 1,048,576 f used
    bf16_t* u_bf  = (bf16_t*)(ws + 6291456);   // [t][d] 2,097,152 f
    bf16_t* dtT   = (bf16_t*)(ws + 8388608);   // [d][t] 2,097,152 f
    bf16_t* h_bf  = (bf16_t*)(ws + 10485760);  // shared with y (h dead after in_proj)
    bf16_t* y_bf  = (bf16_t*)(ws + 10485760);  // [t][d] 2,097,152 f
    float*  bcbuf = ws + 12582912;             // 131,072 f
    bf16_t* Pbuf  = (bf16_t*)(ws + 12845056);  // bf16: 1,048,576 f (w_in aliased; Hinit in place)
    bf16_t* w_in  = (bf16_t*)(ws + 12845056);  // 524,288 f (dead before P written)
    bf16_t* Fbuf  = (bf16_t*)(ws + 14942208);  // bf16: 1,048,576 f (W_all aliased)
    bf16_t* W_all = (bf16_t*)(ws + 14942208);  // N_ALL*1024 bf16 = 589,824 f (dead before F)
    bf16_t* w_out = (bf16_t*)(ws + 17039360);  // 262,144 f

    // 0+1. fused prep: weight converts + Wc + tail + RMSNorm
    prep_kernel<<<6016, 256, 0, stream>>>(in_proj_w, out_proj_w, dt_proj_w, x_proj_w,
                                          x, mask, norm_w, w_in, w_out, W_all, h_bf);
    // 2. in_proj MFMA: u half -> bf16 u_pre[t][d]; z half -> bf16 silu(z) gT[d][t]
    gemm_mfma<3, 128><<<dim3(16, 32), 256, 0, stream>>>(
        h_bf, w_in, u_pre, ROWS, 2 * D_INNER, D_MODEL, nullptr, nullptr, gT, nullptr);
    // 3. causal depthwise conv + SiLU -> u bf16 (8 d/thread)
    conv_silu_kernel<<<(ROWS * D_INNER / 8) / 256, 256, 0, stream>>>(u_pre, conv_w, conv_b, u_bf);
    // 4+5. fused x_proj+dt_proj MFMA: dt -> dtT[d][t] (softplus bf16); bc -> bcbuf fp32
    gemm_mfma<4, 128><<<dim3(N_ALL / 128, 32), 256, 0, stream>>>(
        u_bf, W_all, dtT, ROWS, N_ALL, D_INNER, nullptr, nullptr, bcbuf, dt_proj_b);
    // 6. chunked selective scan (2-way state split, vector dt/g, LDS u, bf16 P/F) -> y bf16
    scan_phase1<<<B_SZ * NCHUNK * 8, 256, 0, stream>>>(dtT, u_bf, bcbuf, A_log, Pbuf, Fbuf);
    scan_phase2<<<NPAIR * D_STATE / 256, 256, 0, stream>>>(Pbuf, Fbuf);
    scan_phase3<<<B_SZ * NCHUNK * 8, 256, 0, stream>>>(dtT, u_bf, bcbuf, gT, A_log, Dw,
                                                       Pbuf, y_bf);
    // 7. out_proj MFMA + residual + mask (128x64 tile, 32x8 -> 256 blocks)
    gemm_mfma<2, 64><<<dim3(8, 32), 256, 0, stream>>>(
        y_bf, w_out, out, ROWS, D_MODEL, D_INNER, x, mask, nullptr, nullptr);
}

// Round 23
// 151.715 us; speedup vs baseline: 1.0390x; 1.0033x over previous
//
#include <hip/hip_runtime.h>
#include <hip/hip_bf16.h>
#include <math.h>

#define D_MODEL 512
#define D_INNER 1024
#define D_STATE 16
#define DT_RANK 32
#define B_SZ 2
#define SEQ 2048
#define ROWS (B_SZ*SEQ)   // 4096
#define EPSV 1e-5f
#define NCHUNK 64
#define CLEN (SEQ/NCHUNK)    // 32
#define NPAIR (B_SZ*D_INNER) // 2048
#define LOG2E 1.44269504088896f
#define N_ALL 1152           // 1024 dt cols + 32 BC cols + 96 zero pad

typedef short bf16x8 __attribute__((ext_vector_type(8)));
typedef float f32x4  __attribute__((ext_vector_type(4)));
typedef __hip_bfloat16 bf16_t;

static __device__ __forceinline__ float bf2f(bf16_t v) { return __bfloat162float(v); }
static __device__ __forceinline__ float bfraw2f(short v) {
    return __uint_as_float(((unsigned)(unsigned short)v) << 16);
}

// bijective XCD-aware swizzle (all grids have nwg % 8 == 0)
static __device__ __forceinline__ void xcd_swizzle(int& bx, int& by) {
    int gx = gridDim.x;
    int nwg = gx * gridDim.y;
    int flat = by * gx + bx;
    int q = nwg >> 3;
    int s = (flat & 7) * q + (flat >> 3);
    bx = s % gx; by = s / gx;
}

// ================= fused prep: weight converts + Wc GEMM + W_all tail + RMSNorm ========
__global__ __launch_bounds__(256) void prep_kernel(
        const float* __restrict__ in_proj_w, const float* __restrict__ out_proj_w,
        const float* __restrict__ dt_proj_w, const float* __restrict__ x_proj_w,
        const float* __restrict__ x, const int* __restrict__ mask,
        const float* __restrict__ norm_w,
        bf16_t* __restrict__ w_in, bf16_t* __restrict__ w_out,
        bf16_t* __restrict__ W_all, bf16_t* __restrict__ h) {
    int bid = blockIdx.x;
    int tid = threadIdx.x;
    if (bid < 1536) {                       // weight conversion
        const float* src = (bid < 1024) ? in_proj_w : out_proj_w;
        bf16_t* dst = (bid < 1024) ? w_in : w_out;
        int i = ((bid < 1024) ? bid : (bid - 1024)) * 256 + tid;
        float4 v = reinterpret_cast<const float4*>(src)[i];
        bf16_t o[4] = {__float2bfloat16(v.x), __float2bfloat16(v.y),
                       __float2bfloat16(v.z), __float2bfloat16(v.w)};
        reinterpret_cast<ushort4*>(dst)[i] = *reinterpret_cast<ushort4*>(o);
    } else if (bid < 1792) {                // Wc = dt_proj_w @ x_proj_w[0:32,:]
        __shared__ float a[64][33];
        __shared__ float b[32][68];
        int blk = bid - 1536;
        int n0 = (blk >> 4) * 64;
        int k0 = (blk & 15) * 64;
        #pragma unroll
        for (int hh = 0; hh < 2; ++hh) {
            int q = tid + hh * 256;
            int r = q >> 3, c = (q & 7) * 4;
            float4 v = *reinterpret_cast<const float4*>(dt_proj_w + (size_t)(n0 + r) * DT_RANK + c);
            a[r][c] = v.x; a[r][c + 1] = v.y; a[r][c + 2] = v.z; a[r][c + 3] = v.w;
            int r2 = q >> 4, c2 = (q & 15) * 4;
            float4 w = *reinterpret_cast<const float4*>(x_proj_w + (size_t)r2 * D_INNER + k0 + c2);
            b[r2][c2] = w.x; b[r2][c2 + 1] = w.y; b[r2][c2 + 2] = w.z; b[r2][c2 + 3] = w.w;
        }
        __syncthreads();
        int ty = tid >> 4, tx = tid & 15;
        float acc[4][4] = {};
        #pragma unroll
        for (int r = 0; r < 32; ++r) {
            float av[4], bv[4];
            #pragma unroll
            for (int i = 0; i < 4; ++i) av[i] = a[ty * 4 + i][r];
            #pragma unroll
            for (int j = 0; j < 4; ++j) bv[j] = b[r][tx * 4 + j];
            #pragma unroll
            for (int i = 0; i < 4; ++i)
                #pragma unroll
                for (int j = 0; j < 4; ++j)
                    acc[i][j] = fmaf(av[i], bv[j], acc[i][j]);
        }
        #pragma unroll
        for (int i = 0; i < 4; ++i) {
            bf16_t o[4];
            #pragma unroll
            for (int j = 0; j < 4; ++j) o[j] = __float2bfloat16(acc[i][j]);
            *reinterpret_cast<ushort4*>(W_all + (size_t)(n0 + ty * 4 + i) * D_INNER + k0 + tx * 4) =
                *reinterpret_cast<ushort4*>(o);
        }
    } else if (bid < 1920) {                // W_all rows [1024,1152): 32 BC rows + 96 zero
        int row = bid - 1792;               // one row per block
        int cq = tid * 4;
        bf16_t o[4] = {};
        if (row < 32) {
            float4 v = *reinterpret_cast<const float4*>(x_proj_w + (size_t)(32 + row) * D_INNER + cq);
            o[0] = __float2bfloat16(v.x); o[1] = __float2bfloat16(v.y);
            o[2] = __float2bfloat16(v.z); o[3] = __float2bfloat16(v.w);
        }
        *reinterpret_cast<ushort4*>(W_all + (size_t)(1024 + row) * D_INNER + cq) =
            *reinterpret_cast<ushort4*>(o);
    } else {                                // RMSNorm + mask -> bf16 h
        __shared__ float red[4];
        int row = bid - 1920;
        const float2 v = reinterpret_cast<const float2*>(x + (size_t)row * D_MODEL)[tid];
        float ss = v.x * v.x + v.y * v.y;
        #pragma unroll
        for (int m = 1; m < 64; m <<= 1) ss += __shfl_xor(ss, m);
        if ((tid & 63) == 0) red[tid >> 6] = ss;
        __syncthreads();
        float tot = red[0] + red[1] + red[2] + red[3];
        float scale = rsqrtf(tot * (1.0f / D_MODEL) + EPSV) * (float)mask[row];
        __hip_bfloat162 o;
        o.x = __float2bfloat16(v.x * scale * norm_w[2 * tid]);
        o.y = __float2bfloat16(v.y * scale * norm_w[2 * tid + 1]);
        reinterpret_cast<__hip_bfloat162*>(h + (size_t)row * D_MODEL)[tid] = o;
    }
}

// ---------------- bf16 MFMA GEMM, 128xTN tile, BK=64, SINGLE-buffer (m97 structure) ----
// launch_bounds(256,3): 16/24 KB LDS -> 3 blocks/CU; cross-block waves hide the
// per-K-step barrier drain (m114 implicit overlap).
// swapped  mfma(bfr,af): lane's 4 regs = 4 consecutive n at fixed m  -> t-major stores
// nonswap  mfma(af,bfr): lane's 4 regs = 4 consecutive m at fixed n  -> TRANSPOSED stores
// MODE 2: swapped. C fp32 = xres + mask[m]*acc
// MODE 3: n0<1024 swapped -> bf16 u_pre[t][d]; n0>=1024 nonswap -> bf16 silu(z) gT[d][t]
// MODE 4: n0<1024 nonswap -> softplus(v+bias[n]) dtT[d][t]; n0>=1024 swapped -> fp32 bc[t][32]
template<int MODE, int TN>
__global__ __launch_bounds__(256, 3) void gemm_mfma(
        const bf16_t* __restrict__ A, const bf16_t* __restrict__ Bw,
        void* __restrict__ Cv, int M, int N, int K,
        const float* __restrict__ xres, const int* __restrict__ mask2,
        void* __restrict__ z2, const float* __restrict__ bias) {
    constexpr int MI  = (TN == 128) ? 4 : 2;   // M-frags per wave
    constexpr int BCH = TN / 32;               // B chunks per wave (chunk = 8 rows x 64 cols)
    __shared__ alignas(16) bf16_t As[128 * 64];
    __shared__ alignas(16) bf16_t Bs[TN * 64];
    const int tid = threadIdx.x;
    const int wid = tid >> 6, lane = tid & 63;
    int bx = blockIdx.x, by = blockIdx.y;
    xcd_swizzle(bx, by);
    const int m0 = by * 128, n0 = bx * TN;
    const int wr = (TN == 128) ? ((wid >> 1) * 64) : (wid * 32);
    const int wc = (TN == 128) ? ((wid & 1) * 64) : 0;

    const bool ns = (MODE == 3) ? (n0 >= D_INNER)
                  : (MODE == 4) ? (n0 < D_INNER) : false;

    f32x4 acc[MI][4];
    #pragma unroll
    for (int i = 0; i < MI; ++i)
        #pragma unroll
        for (int j = 0; j < 4; ++j)
            #pragma unroll
            for (int r = 0; r < 4; ++r) acc[i][j][r] = 0.f;

    const int rrow = lane & 15, kg = lane >> 4;
    const int lrow = lane >> 3;          // 0..7: row within 8-row chunk
    const int cbs = (lane & 7) ^ lrow;   // source colblock (XOR involution on 8 blocks)

    // hoisted LDS read offsets (loop-invariant; static-indexed after unroll)
    int offA[2][MI], offB[2][4];
    #pragma unroll
    for (int kk = 0; kk < 2; ++kk) {
        #pragma unroll
        for (int i = 0; i < MI; ++i) {
            int ra = wr + i * 16 + rrow;
            offA[kk][i] = ra * 64 + (((kk * 4 + kg) ^ (ra & 7)) * 8);
        }
        #pragma unroll
        for (int j = 0; j < 4; ++j) {
            int rb = wc + j * 16 + rrow;
            offB[kk][j] = rb * 64 + (((kk * 4 + kg) ^ (rb & 7)) * 8);
        }
    }
    // hoisted per-lane global staging pointers, advanced by 64 per stage
    const bf16_t* gAp[4];
    const bf16_t* gBp[BCH];
    #pragma unroll
    for (int j = 0; j < 4; ++j) {
        int r = (wid * 4 + j) * 8 + lrow;
        gAp[j] = A + (size_t)(m0 + r) * K + cbs * 8;
    }
    #pragma unroll
    for (int j = 0; j < BCH; ++j) {
        int r = (wid * BCH + j) * 8 + lrow;
        gBp[j] = Bw + (size_t)(n0 + r) * K + cbs * 8;
    }

    auto stage = [&]() {
        #pragma unroll
        for (int j = 0; j < 4; ++j) {
            int c = wid * 4 + j;
            __builtin_amdgcn_global_load_lds(
                (const __attribute__((address_space(1))) void*)gAp[j],
                (__attribute__((address_space(3))) void*)(As + c * 512), 16, 0, 0);
            gAp[j] += 64;
        }
        #pragma unroll
        for (int j = 0; j < BCH; ++j) {
            int c = wid * BCH + j;
            __builtin_amdgcn_global_load_lds(
                (const __attribute__((address_space(1))) void*)gBp[j],
                (__attribute__((address_space(3))) void*)(Bs + c * 512), 16, 0, 0);
            gBp[j] += 64;
        }
    };
    auto computeS = [&]() {
        #pragma unroll
        for (int kk = 0; kk < 2; ++kk) {
            bf16x8 af[MI], bfr[4];
            #pragma unroll
            for (int i = 0; i < MI; ++i)
                af[i] = *reinterpret_cast<const bf16x8*>(As + offA[kk][i]);
            #pragma unroll
            for (int j = 0; j < 4; ++j)
                bfr[j] = *reinterpret_cast<const bf16x8*>(Bs + offB[kk][j]);
            #pragma unroll
            for (int i = 0; i < MI; ++i)
                #pragma unroll
                for (int j = 0; j < 4; ++j)
                    acc[i][j] = __builtin_amdgcn_mfma_f32_16x16x32_bf16(bfr[j], af[i], acc[i][j], 0, 0, 0);
        }
    };
    auto computeNS = [&]() {
        #pragma unroll
        for (int kk = 0; kk < 2; ++kk) {
            bf16x8 af[MI], bfr[4];
            #pragma unroll
            for (int i = 0; i < MI; ++i)
                af[i] = *reinterpret_cast<const bf16x8*>(As + offA[kk][i]);
            #pragma unroll
            for (int j = 0; j < 4; ++j)
                bfr[j] = *reinterpret_cast<const bf16x8*>(Bs + offB[kk][j]);
            #pragma unroll
            for (int i = 0; i < MI; ++i)
                #pragma unroll
                for (int j = 0; j < 4; ++j)
                    acc[i][j] = __builtin_amdgcn_mfma_f32_16x16x32_bf16(af[i], bfr[j], acc[i][j], 0, 0, 0);
        }
    };

    if (ns) {
        for (int k0 = 0; k0 < K; k0 += 64) {
            stage();
            __syncthreads();
            computeNS();
            __syncthreads();
        }
        // transposed epilogue: lane's 4 regs = 4 consecutive m at fixed n
        #pragma unroll
        for (int i = 0; i < MI; ++i) {
            int mb = m0 + wr + i * 16 + (lane >> 4) * 4;
            #pragma unroll
            for (int j = 0; j < 4; ++j) {
                int n = n0 + wc + j * 16 + (lane & 15);
                f32x4 v = acc[i][j];
                bf16_t o[4];
                if (MODE == 3) {          // silu(z) -> gT[d][row]
                    #pragma unroll
                    for (int r = 0; r < 4; ++r) {
                        float zv = v[r];
                        o[r] = __float2bfloat16(zv / (1.f + __expf(-zv)));
                    }
                    *reinterpret_cast<ushort4*>((bf16_t*)z2 + (size_t)(n - D_INNER) * ROWS + mb) =
                        *reinterpret_cast<ushort4*>(o);
                } else {                  // MODE 4: softplus dt -> dtT[d][row]
                    float bs = bias[n];
                    #pragma unroll
                    for (int r = 0; r < 4; ++r) {
                        float s = v[r] + bs;
                        s = (s > 20.f) ? s : __logf(1.f + __expf(s));
                        o[r] = __float2bfloat16(s);
                    }
                    *reinterpret_cast<ushort4*>((bf16_t*)Cv + (size_t)n * ROWS + mb) =
                        *reinterpret_cast<ushort4*>(o);
                }
            }
        }
    } else {
        for (int k0 = 0; k0 < K; k0 += 64) {
            stage();
            __syncthreads();
            computeS();
            __syncthreads();
        }
        // swapped epilogue: lane's 4 regs = 4 consecutive n at fixed m
        #pragma unroll
        for (int i = 0; i < MI; ++i) {
            int m = m0 + wr + i * 16 + (lane & 15);
            #pragma unroll
            for (int j = 0; j < 4; ++j) {
                int nb = n0 + wc + j * 16 + (lane >> 4) * 4;
                f32x4 v = acc[i][j];
                if (MODE == 2) {
                    float mf = (float)mask2[m];
                    float4 xr = *reinterpret_cast<const float4*>(xres + (size_t)m * N + nb);
                    float4 o;
                    o.x = xr.x + mf * v[0]; o.y = xr.y + mf * v[1];
                    o.z = xr.z + mf * v[2]; o.w = xr.w + mf * v[3];
                    *reinterpret_cast<float4*>((float*)Cv + (size_t)m * N + nb) = o;
                } else if (MODE == 3) {   // u_pre half (nb < D_INNER always here)
                    bf16_t o[4];
                    #pragma unroll
                    for (int r = 0; r < 4; ++r) o[r] = __float2bfloat16(v[r]);
                    *reinterpret_cast<ushort4*>((bf16_t*)Cv + (size_t)m * D_INNER + nb) =
                        *reinterpret_cast<ushort4*>(o);
                } else {                  // MODE 4 bc block (nb >= D_INNER always here)
                    if (nb < D_INNER + 32) {
                        float4 o; o.x = v[0]; o.y = v[1]; o.z = v[2]; o.w = v[3];
                        *reinterpret_cast<float4*>((float*)z2 + (size_t)m * 32 + (nb - D_INNER)) = o;
                    }
                }
            }
        }
    }
}

// ---------------- causal depthwise conv (width 4) + bias + SiLU, 8 d per thread ----------
__global__ __launch_bounds__(256) void conv_silu_kernel(const bf16_t* __restrict__ upre,
        const float* __restrict__ conv_w, const float* __restrict__ conv_b,
        bf16_t* __restrict__ u) {
    int idx = blockIdx.x * 256 + threadIdx.x;   // over ROWS*D_INNER/8
    int dq = idx & 127;            // d-group: d0 = dq*8
    int row = idx >> 7;            // b*SEQ + t
    int t = row & (SEQ - 1);
    int d0 = dq * 8;
    const bf16_t* base = upre + (size_t)(row - t) * D_INNER + d0;
    float s_[8];
    {
        float4 b0 = *reinterpret_cast<const float4*>(conv_b + d0);
        float4 b1 = *reinterpret_cast<const float4*>(conv_b + d0 + 4);
        s_[0] = b0.x; s_[1] = b0.y; s_[2] = b0.z; s_[3] = b0.w;
        s_[4] = b1.x; s_[5] = b1.y; s_[6] = b1.z; s_[7] = b1.w;
    }
    #pragma unroll
    for (int j = 0; j < 4; ++j) {
        int tt = t - 3 + j;
        if (tt >= 0) {
            bf16x8 vv = *reinterpret_cast<const bf16x8*>(base + (size_t)tt * D_INNER);
            #pragma unroll
            for (int i = 0; i < 8; ++i)
                s_[i] = fmaf(conv_w[(d0 + i) * 4 + j], bfraw2f(vv[i]), s_[i]);
        }
    }
    bf16_t o[8];
    #pragma unroll
    for (int i = 0; i < 8; ++i) {
        float v = s_[i];
        o[i] = __float2bfloat16(v / (1.f + __expf(-v)));
    }
    *reinterpret_cast<bf16x8*>(u + (size_t)row * D_INNER + d0) =
        *reinterpret_cast<bf16x8*>(o);
}

// ================= chunked selective scan: 2-way split, vector dt/g, LDS-staged u ======
// P/F/Hinit stored in BF16 (chunk-boundary states only; within-chunk math fp32).
__global__ __launch_bounds__(256) void scan_phase1(
        const bf16_t* __restrict__ dtT, const bf16_t* __restrict__ ub,
        const float* __restrict__ bcbuf, const float* __restrict__ A_log,
        bf16_t* __restrict__ P, bf16_t* __restrict__ F) {
    int tid = threadIdx.x;
    int bid = blockIdx.x;
    int dblk = bid & 7, c = (bid >> 3) & (NCHUNK - 1), b = bid >> 9;
    int d = dblk * 128 + (tid >> 1);
    int dloc = tid >> 1;
    int sh = (tid & 1) * 8;
    __shared__ float sBC[CLEN][32];
    __shared__ bf16_t sU[CLEN][128];
    size_t rb = (size_t)b * SEQ + (size_t)c * CLEN;
    {
        int row = tid >> 3, q = tid & 7;
        *reinterpret_cast<float4*>(&sBC[row][q * 4]) =
            *reinterpret_cast<const float4*>(bcbuf + (rb + row) * 32 + q * 4);
    }
    {
        int d0 = dblk * 128;
        #pragma unroll
        for (int hh = 0; hh < 2; ++hh) {
            int s = hh * 256 + tid;
            int row = s >> 4, cb = (s & 15) * 8;
            *reinterpret_cast<bf16x8*>(&sU[row][cb]) =
                *reinterpret_cast<const bf16x8*>(ub + (rb + row) * D_INNER + d0 + cb);
        }
    }
    float A2[8];
    #pragma unroll
    for (int s4 = 0; s4 < 2; ++s4) {
        float4 a = *reinterpret_cast<const float4*>(A_log + d * D_STATE + sh + s4 * 4);
        A2[s4 * 4 + 0] = -expf(a.x) * LOG2E;
        A2[s4 * 4 + 1] = -expf(a.y) * LOG2E;
        A2[s4 * 4 + 2] = -expf(a.z) * LOG2E;
        A2[s4 * 4 + 3] = -expf(a.w) * LOG2E;
    }
    float p[8], f[8];
    #pragma unroll
    for (int s = 0; s < 8; ++s) { p[s] = 1.f; f[s] = 0.f; }
    const bf16_t* dtp = dtT + (size_t)d * ROWS + rb;
    __syncthreads();
    bf16x8 dtA = *reinterpret_cast<const bf16x8*>(dtp);
    for (int tb = 0; tb < CLEN; tb += 8) {
        bf16x8 dtB = dtA;
        if (tb + 8 < CLEN) dtB = *reinterpret_cast<const bf16x8*>(dtp + tb + 8);
        #pragma unroll
        for (int j = 0; j < 8; ++j) {
            float dtv = bfraw2f(dtA[j]);
            float dtu = dtv * bf2f(sU[tb + j][dloc]);
            #pragma unroll
            for (int s = 0; s < 8; ++s) {
                float e = exp2f(dtv * A2[s]);
                p[s] *= e;
                f[s] = fmaf(e, f[s], sBC[tb + j][sh + s] * dtu);
            }
        }
        dtA = dtB;
    }
    size_t o = ((size_t)(b * D_INNER + d) * NCHUNK + c) * D_STATE + sh;
    bf16_t po[8], fo[8];
    #pragma unroll
    for (int s = 0; s < 8; ++s) {
        po[s] = __float2bfloat16(p[s]);
        fo[s] = __float2bfloat16(f[s]);
    }
    *reinterpret_cast<bf16x8*>(P + o) = *reinterpret_cast<bf16x8*>(po);
    *reinterpret_cast<bf16x8*>(F + o) = *reinterpret_cast<bf16x8*>(fo);
}

// one thread per (pair,s) chain, 8-deep load pipeline; writes Hinit IN PLACE over P (bf16)
__global__ __launch_bounds__(256) void scan_phase2(
        bf16_t* __restrict__ P, const bf16_t* __restrict__ F) {
    int idx = blockIdx.x * 256 + threadIdx.x;   // NPAIR*16
    int pair = idx >> 4, s = idx & 15;
    size_t base = (size_t)pair * NCHUNK * D_STATE + s;
    float pp[8], ff[8];
    #pragma unroll
    for (int j = 0; j < 8; ++j) {
        pp[j] = bf2f(P[base + (size_t)j * D_STATE]);
        ff[j] = bf2f(F[base + (size_t)j * D_STATE]);
    }
    float h = 0.f;
    #pragma unroll
    for (int cb = 0; cb < 8; ++cb) {
        #pragma unroll
        for (int j = 0; j < 8; ++j) {
            int c = cb * 8 + j;
            float p = pp[j], f = ff[j];
            if (cb < 7) {
                pp[j] = bf2f(P[base + (size_t)(c + 8) * D_STATE]);
                ff[j] = bf2f(F[base + (size_t)(c + 8) * D_STATE]);
            }
            P[base + (size_t)c * D_STATE] = __float2bfloat16(h);   // Hinit
            h = fmaf(p, h, f);
        }
    }
}

__global__ __launch_bounds__(256) void scan_phase3(
        const bf16_t* __restrict__ dtT, const bf16_t* __restrict__ ub,
        const float* __restrict__ bcbuf, const bf16_t* __restrict__ gT,  // silu(z), [d][row]
        const float* __restrict__ A_log, const float* __restrict__ Dw,
        const bf16_t* __restrict__ Hinit, bf16_t* __restrict__ ybuf) {
    int tid = threadIdx.x;
    int bid = blockIdx.x;
    int dblk = bid & 7, c = (bid >> 3) & (NCHUNK - 1), b = bid >> 9;
    int d = dblk * 128 + (tid >> 1);
    int dloc = tid >> 1;
    int sh = (tid & 1) * 8;
    __shared__ float sBC[CLEN][32];
    __shared__ bf16_t sU[CLEN][128];
    size_t rb = (size_t)b * SEQ + (size_t)c * CLEN;
    {
        int row = tid >> 3, q = tid & 7;
        *reinterpret_cast<float4*>(&sBC[row][q * 4]) =
            *reinterpret_cast<const float4*>(bcbuf + (rb + row) * 32 + q * 4);
    }
    {
        int d0 = dblk * 128;
        #pragma unroll
        for (int hh = 0; hh < 2; ++hh) {
            int s = hh * 256 + tid;
            int row = s >> 4, cb = (s & 15) * 8;
            *reinterpret_cast<bf16x8*>(&sU[row][cb]) =
                *reinterpret_cast<const bf16x8*>(ub + (rb + row) * D_INNER + d0 + cb);
        }
    }
    float A2[8];
    #pragma unroll
    for (int s4 = 0; s4 < 2; ++s4) {
        float4 a = *reinterpret_cast<const float4*>(A_log + d * D_STATE + sh + s4 * 4);
        A2[s4 * 4 + 0] = -expf(a.x) * LOG2E;
        A2[s4 * 4 + 1] = -expf(a.y) * LOG2E;
        A2[s4 * 4 + 2] = -expf(a.z) * LOG2E;
        A2[s4 * 4 + 3] = -expf(a.w) * LOG2E;
    }
    float Dd = Dw[d];
    float st[8];
    size_t o = ((size_t)(b * D_INNER + d) * NCHUNK + c) * D_STATE + sh;
    {
        bf16x8 hv = *reinterpret_cast<const bf16x8*>(Hinit + o);
        #pragma unroll
        for (int s = 0; s < 8; ++s) st[s] = bfraw2f(hv[s]);
    }
    const bf16_t* dtp = dtT + (size_t)d * ROWS + rb;
    const bf16_t* gp  = gT  + (size_t)d * ROWS + rb;
    bf16_t* yp = ybuf + rb * D_INNER + d;
    __syncthreads();
    bf16x8 dtA = *reinterpret_cast<const bf16x8*>(dtp);
    bf16x8 gA  = *reinterpret_cast<const bf16x8*>(gp);
    for (int tb = 0; tb < CLEN; tb += 8) {
        bf16x8 dtB = dtA, gB = gA;
        if (tb + 8 < CLEN) {
            dtB = *reinterpret_cast<const bf16x8*>(dtp + tb + 8);
            gB  = *reinterpret_cast<const bf16x8*>(gp + tb + 8);
        }
        #pragma unroll
        for (int j = 0; j < 8; ++j) {
            float dtv = bfraw2f(dtA[j]);
            float uv = bf2f(sU[tb + j][dloc]);
            float dtu = dtv * uv;
            float y = 0.f;
            #pragma unroll
            for (int s = 0; s < 8; ++s) {
                float e = exp2f(dtv * A2[s]);
                st[s] = fmaf(e, st[s], sBC[tb + j][sh + s] * dtu);
                y = fmaf(st[s], sBC[tb + j][16 + sh + s], y);
            }
            y += __shfl_xor(y, 1);       // combine the two state halves of this d
            if ((tid & 1) == 0) {
                yp[(size_t)(tb + j) * D_INNER] =
                    __float2bfloat16((y + Dd * uv) * bfraw2f(gA[j]));
            }
        }
        dtA = dtB; gA = gB;
    }
}

extern "C" void kernel_launch(void* const* d_in, const int* in_sizes, int n_in,
                              void* d_out, int out_size, void* d_ws, size_t ws_size,
                              hipStream_t stream) {
    const float* x          = (const float*)d_in[0];
    const int*   mask       = (const int*)d_in[1];
    const float* norm_w     = (const float*)d_in[2];
    const float* in_proj_w  = (const float*)d_in[3];
    const float* conv_w     = (const float*)d_in[4];
    const float* conv_b     = (const float*)d_in[5];
    const float* x_proj_w   = (const float*)d_in[6];
    const float* dt_proj_w  = (const float*)d_in[7];
    const float* dt_proj_b  = (const float*)d_in[8];
    const float* A_log      = (const float*)d_in[9];
    const float* Dw         = (const float*)d_in[10];
    const float* out_proj_w = (const float*)d_in[11];
    float* out = (float*)d_out;
    float* ws  = (float*)d_ws;

    // workspace layout (float units), lifetime-shared:
    bf16_t* u_pre = (bf16_t*)ws;               // [t][d] 2,097,152 f
    bf16_t* gT    = (bf16_t*)(ws + 2097152);   // silu(z) [d][t], 1,048,576 f used
    bf16_t* u_bf  = (bf16_t*)(ws + 6291456);   // [t][d] 2,097,152 f
    bf16_t* dtT   = (bf16_t*)(ws + 8388608);   // [d][t] 2,097,152 f
    bf16_t* h_bf  = (bf16_t*)(ws + 10485760);  // shared with y (h dead after in_proj)
    bf16_t* y_bf  = (bf16_t*)(ws + 10485760);  // [t][d] 2,097,152 f
    float*  bcbuf = ws + 12582912;             // 131,072 f
    bf16_t* Pbuf  = (bf16_t*)(ws + 12845056);  // bf16: 1,048,576 f (w_in aliased; Hinit in place)
    bf16_t* w_in  = (bf16_t*)(ws + 12845056);  // 524,288 f (dead before P written)
    bf16_t* Fbuf  = (bf16_t*)(ws + 14942208);  // bf16: 1,048,576 f (W_all aliased)
    bf16_t* W_all = (bf16_t*)(ws + 14942208);  // N_ALL*1024 bf16 = 589,824 f (dead before F)
    bf16_t* w_out = (bf16_t*)(ws + 17039360);  // 262,144 f

    // 0+1. fused prep: weight converts + Wc + tail + RMSNorm
    prep_kernel<<<6016, 256, 0, stream>>>(in_proj_w, out_proj_w, dt_proj_w, x_proj_w,
                                          x, mask, norm_w, w_in, w_out, W_all, h_bf);
    // 2. in_proj MFMA: u half -> bf16 u_pre[t][d]; z half -> bf16 silu(z) gT[d][t]
    gemm_mfma<3, 128><<<dim3(16, 32), 256, 0, stream>>>(
        h_bf, w_in, u_pre, ROWS, 2 * D_INNER, D_MODEL, nullptr, nullptr, gT, nullptr);
    // 3. causal depthwise conv + SiLU -> u bf16 (8 d/thread)
    conv_silu_kernel<<<(ROWS * D_INNER / 8) / 256, 256, 0, stream>>>(u_pre, conv_w, conv_b, u_bf);
    // 4+5. fused x_proj+dt_proj MFMA: dt -> dtT[d][t] (softplus bf16); bc -> bcbuf fp32
    gemm_mfma<4, 128><<<dim3(N_ALL / 128, 32), 256, 0, stream>>>(
        u_bf, W_all, dtT, ROWS, N_ALL, D_INNER, nullptr, nullptr, bcbuf, dt_proj_b);
    // 6. chunked selective scan (2-way state split, vector dt/g, LDS u, bf16 P/F) -> y bf16
    scan_phase1<<<B_SZ * NCHUNK * 8, 256, 0, stream>>>(dtT, u_bf, bcbuf, A_log, Pbuf, Fbuf);
    scan_phase2<<<NPAIR * D_STATE / 256, 256, 0, stream>>>(Pbuf, Fbuf);
    scan_phase3<<<B_SZ * NCHUNK * 8, 256, 0, stream>>>(dtT, u_bf, bcbuf, gT, A_log, Dw,
                                                       Pbuf, y_bf);
    // 7. out_proj MFMA + residual + mask (128x64 tile, 32x8 -> 256 blocks)
    gemm_mfma<2, 64><<<dim3(8, 32), 256, 0, stream>>>(
        y_bf, w_out, out, ROWS, D_MODEL, D_INNER, x, mask, nullptr, nullptr);
}